// Round 9
// baseline (536.171 us; speedup 1.0000x reference)
//
#include <hip/hip_runtime.h>

#define B_ 8
#define T_ 2048
#define D_ 768
#define H_ 12
#define HS_ 64
#define LN_EPS 1e-5f
#define NC 32   // chunks
#define TC 64   // timesteps per chunk

typedef __attribute__((ext_vector_type(8))) short bf16x8;
typedef __attribute__((ext_vector_type(4))) float f32x4;

__device__ __forceinline__ ushort f2bf(float f) {
  unsigned u = __builtin_bit_cast(unsigned, f);
  unsigned r = (u + 0x7FFFu + ((u >> 16) & 1u)) >> 16;
  return (ushort)r;
}
__device__ __forceinline__ float bf2f(ushort u) {
  return __builtin_bit_cast(float, ((unsigned)u) << 16);
}

// fragment address: element (row t, col i) of a 64x64 tile in MFMA A/B-frag
// layout (m/n = t, k = i). 8 frags x 512 halves.
__device__ __forceinline__ int fragaddr(int t, int i) {
  return ((t >> 4) * 2 + (i >> 5)) * 512 + ((((i >> 3) & 3) * 16) + (t & 15)) * 8 + (i & 7);
}
__device__ __forceinline__ int fragswz(int i) {
  return (((i >> 3) & 3) << 3) ^ (((i >> 5) & 1) << 5);
}

// ---------------- canary ----------------
__global__ __launch_bounds__(256) void zero_out_kernel(float* __restrict__ out, int n) {
  for (int i = blockIdx.x * 256 + threadIdx.x; i < n; i += gridDim.x * 256)
    out[i] = 0.f;
}

// ---------------- weight cast: 5 sources -> slots {0,1,2,4,5} ----------------
__global__ __launch_bounds__(256) void cast5_kernel(
    const float* __restrict__ w0, const float* __restrict__ w1,
    const float* __restrict__ w2, const float* __restrict__ w3,
    const float* __restrict__ w4, ushort* __restrict__ dst) {
  const float* srcs[5] = {w0, w1, w2, w3, w4};
  const int slots[5] = {0, 1, 2, 4, 5};
  const float* src = srcs[blockIdx.y];
  ushort* d = dst + (size_t)slots[blockIdx.y] * 589824;
  int idx = (blockIdx.x * 256 + threadIdx.x) * 4;
  float4 v = *reinterpret_cast<const float4*>(src + idx);
  ushort4 o;
  o.x = f2bf(v.x); o.y = f2bf(v.y); o.z = f2bf(v.z); o.w = f2bf(v.w);
  *reinterpret_cast<ushort4*>(d + idx) = o;
}

// ---------------- transpose-cast: WxT[d][e] = Wx[e][d] ----------------
__global__ __launch_bounds__(256) void transpose_cast_kernel(
    const float* __restrict__ src, ushort* __restrict__ dst) {
  __shared__ ushort tile[32][33];
  const int bx = blockIdx.x * 32;
  const int by = blockIdx.y * 32;
  const int tx = threadIdx.x & 31, ty = threadIdx.x >> 5;
#pragma unroll
  for (int r = 0; r < 32; r += 8)
    tile[ty + r][tx] = f2bf(src[(size_t)(by + ty + r) * 768 + bx + tx]);
  __syncthreads();
#pragma unroll
  for (int r = 0; r < 32; r += 8)
    dst[(size_t)(bx + ty + r) * 768 + by + tx] = tile[tx][ty + r];
}

// ---------------- LayerNorm ----------------
__global__ __launch_bounds__(256) void ln_kernel(
    const float* __restrict__ x, const float* __restrict__ gamma,
    const float* __restrict__ beta, ushort* __restrict__ xn) {
  const int wv = threadIdx.x >> 6;
  const int lane = threadIdx.x & 63;
  const int row = blockIdx.x * 4 + wv;
  const float* xr = x + (size_t)row * D_;
  float4 a[3];
#pragma unroll
  for (int s = 0; s < 3; ++s)
    a[s] = *reinterpret_cast<const float4*>(xr + s * 256 + lane * 4);
  float sum = 0.f;
#pragma unroll
  for (int s = 0; s < 3; ++s) sum += a[s].x + a[s].y + a[s].z + a[s].w;
#pragma unroll
  for (int off = 32; off; off >>= 1) sum += __shfl_xor(sum, off);
  float mu = sum * (1.f / 768.f);
  float vs = 0.f;
#pragma unroll
  for (int s = 0; s < 3; ++s) {
    float dx = a[s].x - mu, dy = a[s].y - mu, dz = a[s].z - mu, dw = a[s].w - mu;
    vs += dx * dx + dy * dy + dz * dz + dw * dw;
  }
#pragma unroll
  for (int off = 32; off; off >>= 1) vs += __shfl_xor(vs, off);
  float rs = rsqrtf(vs * (1.f / 768.f) + LN_EPS);
  ushort* orow = xn + (size_t)row * D_;
#pragma unroll
  for (int s = 0; s < 3; ++s) {
    int col = s * 256 + lane * 4;
    float4 g = *reinterpret_cast<const float4*>(gamma + col);
    float4 bb = *reinterpret_cast<const float4*>(beta + col);
    ushort4 o;
    o.x = f2bf((a[s].x - mu) * rs * g.x + bb.x);
    o.y = f2bf((a[s].y - mu) * rs * g.y + bb.y);
    o.z = f2bf((a[s].z - mu) * rs * g.z + bb.z);
    o.w = f2bf((a[s].w - mu) * rs * g.w + bb.w);
    *reinterpret_cast<ushort4*>(orow + col) = o;
  }
}

// ---------------- 256x256 8-phase bf16 MFMA GEMM (r6/r8-proven schedule) -----
// C[m,n] = sum_k A[m,k]*W[n,k].  K=768. 512 threads = 8 waves (2M x 4N).
// modes: 0 fp32 plain
//        5 cat -> sel0: d0 bf16 | sel1: d1 v FRAG layout | sel2: d2 sigmoid bf16
//                 sel3: d3 bf16 plain (z)
__global__ __launch_bounds__(512, 2) void gemm256(
    const ushort* __restrict__ A, const ushort* __restrict__ W,
    float* __restrict__ Cf,
    ushort* __restrict__ d0, ushort* __restrict__ d1,
    ushort* __restrict__ d2, ushort* __restrict__ d3, int mode) {
  __shared__ __align__(16) ushort lds[65536];  // 128 KiB
  const int tid = threadIdx.x;
  const int wid = tid >> 6;
  const int lane = tid & 63;
  const int wr = wid >> 2, wc = wid & 3;
  const int fr = lane & 15, fq = lane >> 4;
  const int m0 = blockIdx.x * 256, n0 = blockIdx.y * 256;
  const int strow = tid >> 3;
  const int stblk = tid & 7;

  const int RA0 = wr * 8192;
  const int RA1 = 32768 + wr * 8192;
  const int RB0 = 16384 + (wc >> 1) * 8192 + (wc & 1) * 4096;
  const int RB1 = 49152 + (wc >> 1) * 8192 + (wc & 1) * 4096;

  f32x4 acc[8][4];
#pragma unroll
  for (int m = 0; m < 8; ++m)
#pragma unroll
    for (int n = 0; n < 4; ++n) acc[m][n] = (f32x4){0.f, 0.f, 0.f, 0.f};

#define STAGE_HALF(gb, grow0, kk0, roff)                                          \
  {                                                                               \
    _Pragma("unroll") for (int j = 0; j < 2; ++j) {                               \
      const int lr_ = j * 64 + strow;                                             \
      const int bs_ = stblk ^ (lr_ & 7);                                          \
      const ushort* s_ = (gb) + (size_t)((grow0) + lr_) * 768 + (kk0) + bs_ * 8;  \
      __builtin_amdgcn_global_load_lds(                                           \
          (const __attribute__((address_space(1))) void*)s_,                      \
          (__attribute__((address_space(3))) void*)(lds + (roff) + j * 4096 + wid * 512), \
          16, 0, 0);                                                              \
    }                                                                             \
  }

#define LDF(dst, base, rf, kk)                                                    \
  dst = *reinterpret_cast<const bf16x8*>(                                         \
      lds + (base) + ((rf)*16 + fr) * 64 + ((((kk)*4 + fq) ^ (fr & 7)) * 8));

#define MFMA_Q(mb, nb, aa, bb)                                                    \
  __builtin_amdgcn_s_setprio(1);                                                  \
  _Pragma("unroll") for (int m_ = 0; m_ < 4; ++m_)                                \
  _Pragma("unroll") for (int n_ = 0; n_ < 2; ++n_)                                \
  _Pragma("unroll") for (int k_ = 0; k_ < 2; ++k_)                                \
    acc[(mb) + m_][(nb) + n_] = __builtin_amdgcn_mfma_f32_16x16x32_bf16(          \
        aa[m_][k_], bb[n_][k_], acc[(mb) + m_][(nb) + n_], 0, 0, 0);              \
  __builtin_amdgcn_s_setprio(0);

  STAGE_HALF(A, m0, 0, 0);
  STAGE_HALF(A, m0 + 128, 0, 8192);
  STAGE_HALF(W, n0, 0, 16384);
  STAGE_HALF(W, n0 + 128, 0, 24576);
  STAGE_HALF(W, n0, 64, 49152);
  STAGE_HALF(W, n0 + 128, 64, 57344);
  asm volatile("s_waitcnt vmcnt(4)" ::: "memory");
  __builtin_amdgcn_s_barrier();

  bf16x8 aL[4][2], aH[4][2], bL[2][2], bH[2][2];

  for (int i = 0; i < 6; ++i) {
    const int kQ = (2 * i + 1) * 64;
    const int kP2 = (2 * i + 2 <= 11 ? 2 * i + 2 : 11) * 64;
    const int kQ2 = (2 * i + 3 <= 11 ? 2 * i + 3 : 11) * 64;

    STAGE_HALF(A, m0, kQ, 32768);
#pragma unroll
    for (int m = 0; m < 4; ++m) { LDF(aL[m][0], RA0, m, 0); LDF(aL[m][1], RA0, m, 1); }
#pragma unroll
    for (int n = 0; n < 2; ++n) { LDF(bL[n][0], RB0, n, 0); LDF(bL[n][1], RB0, n, 1); }
    __builtin_amdgcn_s_barrier();
    MFMA_Q(0, 0, aL, bL);
    __builtin_amdgcn_s_barrier();

    STAGE_HALF(A, m0 + 128, kQ, 40960);
#pragma unroll
    for (int n = 0; n < 2; ++n) { LDF(bH[n][0], RB0, n + 2, 0); LDF(bH[n][1], RB0, n + 2, 1); }
    __builtin_amdgcn_s_barrier();
    MFMA_Q(0, 2, aL, bH);
    __builtin_amdgcn_s_barrier();

    STAGE_HALF(W, n0, kP2, 16384);
#pragma unroll
    for (int m = 0; m < 4; ++m) { LDF(aH[m][0], RA0, m + 4, 0); LDF(aH[m][1], RA0, m + 4, 1); }
    __builtin_amdgcn_s_barrier();
    MFMA_Q(4, 0, aH, bL);
    __builtin_amdgcn_s_barrier();

    STAGE_HALF(W, n0 + 128, kP2, 24576);
    __builtin_amdgcn_s_barrier();
    MFMA_Q(4, 2, aH, bH);
    asm volatile("s_waitcnt vmcnt(4)" ::: "memory");
    __builtin_amdgcn_s_barrier();

    STAGE_HALF(A, m0, kP2, 0);
#pragma unroll
    for (int m = 0; m < 4; ++m) { LDF(aL[m][0], RA1, m, 0); LDF(aL[m][1], RA1, m, 1); }
#pragma unroll
    for (int n = 0; n < 2; ++n) { LDF(bL[n][0], RB1, n, 0); LDF(bL[n][1], RB1, n, 1); }
    __builtin_amdgcn_s_barrier();
    MFMA_Q(0, 0, aL, bL);
    __builtin_amdgcn_s_barrier();

    STAGE_HALF(A, m0 + 128, kP2, 8192);
#pragma unroll
    for (int n = 0; n < 2; ++n) { LDF(bH[n][0], RB1, n + 2, 0); LDF(bH[n][1], RB1, n + 2, 1); }
    __builtin_amdgcn_s_barrier();
    MFMA_Q(0, 2, aL, bH);
    __builtin_amdgcn_s_barrier();

    STAGE_HALF(W, n0, kQ2, 49152);
#pragma unroll
    for (int m = 0; m < 4; ++m) { LDF(aH[m][0], RA1, m + 4, 0); LDF(aH[m][1], RA1, m + 4, 1); }
    __builtin_amdgcn_s_barrier();
    MFMA_Q(4, 0, aH, bL);
    __builtin_amdgcn_s_barrier();

    STAGE_HALF(W, n0 + 128, kQ2, 57344);
    __builtin_amdgcn_s_barrier();
    MFMA_Q(4, 2, aH, bH);
    asm volatile("s_waitcnt vmcnt(4)" ::: "memory");
    __builtin_amdgcn_s_barrier();
  }

  // ---- epilogue ----
  const int r0 = fq * 4;
  if (mode == 5) {
    const int sel = n0 >= 2304 ? 3 : n0 >= 1536 ? 2 : n0 >= 768 ? 1 : 0;
    const int nb = n0 - sel * 768;
    if (sel == 1) {
#pragma unroll
      for (int mf = 0; mf < 8; ++mf)
#pragma unroll
        for (int nf = 0; nf < 4; ++nf) {
          int gr = m0 + wr * 128 + mf * 16 + r0;
          int gc = nb + wc * 64 + nf * 16 + fr;
          int b = gr >> 11, t = gr & 2047;
          int c = t >> 6, s0 = t & 63;
          int h = gc >> 6, j = gc & 63;
          size_t addr = ((size_t)((b * 12 + h) * 32 + c)) * 4096 +
                        (size_t)(((j >> 4) * 2 + (s0 >> 5)) * 512 +
                                 (((s0 >> 3) & 3) * 16 + (j & 15)) * 8 + (s0 & 7));
          ushort4 o;
          o.x = f2bf(acc[mf][nf][0]); o.y = f2bf(acc[mf][nf][1]);
          o.z = f2bf(acc[mf][nf][2]); o.w = f2bf(acc[mf][nf][3]);
          *reinterpret_cast<ushort4*>(d1 + addr) = o;
        }
    } else {
      ushort* dst = sel == 0 ? d0 : sel == 2 ? d2 : d3;
      const bool sig = (sel == 2);
#pragma unroll
      for (int mf = 0; mf < 8; ++mf)
#pragma unroll
        for (int nf = 0; nf < 4; ++nf) {
          int gr = m0 + wr * 128 + mf * 16 + r0;
          int gc = nb + wc * 64 + nf * 16 + fr;
#pragma unroll
          for (int rr = 0; rr < 4; ++rr) {
            float v = acc[mf][nf][rr];
            if (sig) v = 1.f / (1.f + __expf(-v));
            dst[(size_t)(gr + rr) * 768 + gc] = f2bf(v);
          }
        }
    }
  } else {
#pragma unroll
    for (int mf = 0; mf < 8; ++mf)
#pragma unroll
      for (int nf = 0; nf < 4; ++nf) {
        int gr = m0 + wr * 128 + mf * 16 + r0;
        int gc = n0 + wc * 64 + nf * 16 + fr;
#pragma unroll
        for (int rr = 0; rr < 4; ++rr)
          Cf[(size_t)(gr + rr) * 768 + gc] = acc[mf][nf][rr];
      }
  }
#undef STAGE_HALF
#undef LDF
#undef MFMA_Q
}

// ---------------- fused selective scan: one block per (b,h), S in registers --
// Per chunk: d_t[i]=sigmoid(-(z+bw_h)); a=cumprod(d); kA=k*a, kIA=k/a;
// y = kA.S0f + causal(kA.kIA^T).V ; Mc = kIA^T.V ; S = aend*(S+Mc).
__global__ void scan_fused(
    const ushort* __restrict__ kb, const ushort* __restrict__ zb,
    const ushort* __restrict__ vbF, const ushort* __restrict__ rb,
    const float* __restrict__ bwp, ushort* __restrict__ yrow) {
  __shared__ ushort kt[64 * 72];
  __shared__ ushort zt[64 * 72];
  __shared__ ushort kAf[4096];
  __shared__ ushort kIAfB[4096];
  __shared__ ushort kIAfA[4096];
  __shared__ ushort Am[64 * 72];
  __shared__ ushort S0f[4096];
  __shared__ float part[256];
  __shared__ float ae[64];

  const int bh = blockIdx.x;
  const int b = bh / H_, h = bh % H_;
  const int tid = threadIdx.x;
  const int w = tid >> 6, lane = tid & 63;
  const int fr = lane & 15, fq = lane >> 4;
  const int row = tid >> 2, c16 = (tid & 3) * 16;
  const float bwh = bwp[h * 64];
  const int swz = fragswz(lane);

  // init S0f = 0, S = 0
  {
    uint4 z4 = {0, 0, 0, 0};
    *reinterpret_cast<uint4*>(&S0f[tid * 16]) = z4;
    *reinterpret_cast<uint4*>(&S0f[tid * 16 + 8]) = z4;
  }
  f32x4 S[4];
#pragma unroll
  for (int nf = 0; nf < 4; ++nf) S[nf] = (f32x4){0.f, 0.f, 0.f, 0.f};

  uint4 kA0, kA1, zA0, zA1, kB0, kB1, zB0, zB1;
  bf16x8 vA[8], vB[8];

#define LOADK(cc, k0, k1, z0, z1)                                                 \
  {                                                                               \
    int cl_ = (cc) < NC ? (cc) : NC - 1;                                          \
    const ushort* gk_ = kb + ((size_t)(b * T_ + cl_ * TC + row)) * 768 + h * 64 + c16; \
    const ushort* gz_ = zb + ((size_t)(b * T_ + cl_ * TC + row)) * 768 + h * 64 + c16; \
    k0 = *(const uint4*)gk_; k1 = *(const uint4*)(gk_ + 8);                       \
    z0 = *(const uint4*)gz_; z1 = *(const uint4*)(gz_ + 8);                       \
  }

#define LOADV(cc, vfr)                                                            \
  {                                                                               \
    int cl_ = (cc) < NC ? (cc) : NC - 1;                                          \
    const ushort* vch_ = vbF + ((size_t)bh * NC + cl_) * 4096;                    \
    _Pragma("unroll") for (int f = 0; f < 8; ++f)                                 \
      vfr[f] = *reinterpret_cast<const bf16x8*>(vch_ + f * 512 + lane * 8);       \
  }

#define STAGE(k0, k1, z0, z1)                                                     \
  {                                                                               \
    *reinterpret_cast<uint4*>(&kt[row * 72 + c16]) = k0;                          \
    *reinterpret_cast<uint4*>(&kt[row * 72 + c16 + 8]) = k1;                      \
    *reinterpret_cast<uint4*>(&zt[row * 72 + c16]) = z0;                          \
    *reinterpret_cast<uint4*>(&zt[row * 72 + c16 + 8]) = z1;                      \
  }

#define COMPUTE(cc, vfr)                                                          \
  {                                                                               \
    const int c_ = (cc);                                                          \
    /* r loads issued early (hidden under cumprod+A-mat) */                       \
    ushort rr[16];                                                                \
    {                                                                             \
      const ushort* rrow_ = rb + ((size_t)(b * T_ + c_ * TC)) * 768 + h * 64;     \
      _Pragma("unroll") for (int tp = 0; tp < 4; ++tp)                            \
      _Pragma("unroll") for (int nf = 0; nf < 4; ++nf)                            \
        rr[tp * 4 + nf] = rrow_[(size_t)(w * 16 + fq * 4 + tp) * 768 + nf * 16 + fr]; \
    }                                                                             \
    float dreg[16];                                                               \
    float p_ = 1.f;                                                               \
    _Pragma("unroll") for (int tt = 0; tt < 16; ++tt) {                           \
      float z_ = bf2f(zt[(w * 16 + tt) * 72 + lane]);                             \
      float d_ = 1.f / (1.f + __expf(z_ + bwh));                                  \
      dreg[tt] = d_;                                                              \
      p_ *= d_;                                                                   \
    }                                                                             \
    part[w * 64 + lane] = p_;                                                     \
    __syncthreads();                                                              \
    float a_ = 1.f;                                                               \
    for (int w2 = 0; w2 < w; ++w2) a_ *= part[w2 * 64 + lane];                    \
    if (w == 0)                                                                   \
      ae[lane] = part[lane] * part[64 + lane] * part[128 + lane] * part[192 + lane]; \
    _Pragma("unroll") for (int tt = 0; tt < 16; ++tt) {                           \
      int t_ = w * 16 + tt;                                                       \
      float k_ = bf2f(kt[t_ * 72 + lane]);                                        \
      a_ *= dreg[tt];                                                             \
      int ad_ = fragaddr(t_, lane) ^ swz;                                         \
      kAf[ad_] = f2bf(k_ * a_);                                                   \
      ushort ki_ = f2bf(k_ / a_);                                                 \
      kIAfB[ad_] = ki_;                                                           \
      kIAfA[fragaddr(lane, t_)] = ki_;                                            \
    }                                                                             \
    __syncthreads();                                                              \
    bf16x8 af[2];                                                                 \
    _Pragma("unroll") for (int kk = 0; kk < 2; ++kk) {                            \
      int ra_ = ((w * 2 + kk) * 512 + lane * 8) ^ (((lane >> 4) << 3) ^ (kk << 5)); \
      af[kk] = *reinterpret_cast<const bf16x8*>(&kAf[ra_]);                       \
    }                                                                             \
    {                                                                             \
      f32x4 accA[4];                                                              \
      _Pragma("unroll") for (int nf = 0; nf < 4; ++nf)                            \
        accA[nf] = (f32x4){0.f, 0.f, 0.f, 0.f};                                   \
      _Pragma("unroll") for (int kk = 0; kk < 2; ++kk)                            \
      _Pragma("unroll") for (int nf = 0; nf < 4; ++nf) {                          \
        int rb8_ = ((nf * 2 + kk) * 512 + lane * 8) ^ (((lane >> 4) << 3) ^ (kk << 5)); \
        bf16x8 b8_ = *reinterpret_cast<const bf16x8*>(&kIAfB[rb8_]);              \
        accA[nf] = __builtin_amdgcn_mfma_f32_16x16x32_bf16(af[kk], b8_, accA[nf], 0, 0, 0); \
      }                                                                           \
      _Pragma("unroll") for (int nf = 0; nf < 4; ++nf)                            \
      _Pragma("unroll") for (int q = 0; q < 4; ++q) {                             \
        int t_ = w * 16 + fq * 4 + q;                                             \
        int s_ = nf * 16 + fr;                                                    \
        Am[t_ * 72 + s_] = f2bf((s_ <= t_) ? accA[nf][q] : 0.f);                  \
      }                                                                           \
    }                                                                             \
    __syncthreads();                                                              \
    f32x4 accY[4];                                                                \
    _Pragma("unroll") for (int nf = 0; nf < 4; ++nf)                              \
      accY[nf] = (f32x4){0.f, 0.f, 0.f, 0.f};                                     \
    _Pragma("unroll") for (int kk = 0; kk < 2; ++kk)                              \
    _Pragma("unroll") for (int nf = 0; nf < 4; ++nf) {                            \
      bf16x8 b8_ = *reinterpret_cast<const bf16x8*>(&S0f[(nf * 2 + kk) * 512 + lane * 8]); \
      accY[nf] = __builtin_amdgcn_mfma_f32_16x16x32_bf16(af[kk], b8_, accY[nf], 0, 0, 0); \
    }                                                                             \
    _Pragma("unroll") for (int kk = 0; kk < 2; ++kk) {                            \
      bf16x8 am8_ = *reinterpret_cast<const bf16x8*>(&Am[(w * 16 + fr) * 72 + kk * 32 + fq * 8]); \
      _Pragma("unroll") for (int nf = 0; nf < 4; ++nf)                            \
        accY[nf] = __builtin_amdgcn_mfma_f32_16x16x32_bf16(am8_, vfr[nf * 2 + kk], accY[nf], 0, 0, 0); \
    }                                                                             \
    _Pragma("unroll") for (int nf = 0; nf < 4; ++nf)                              \
    _Pragma("unroll") for (int q = 0; q < 4; ++q) {                               \
      int t_ = w * 16 + fq * 4 + q;                                               \
      int j_ = nf * 16 + fr;                                                      \
      size_t go_ = ((size_t)(b * T_ + c_ * TC + t_)) * 768 + h * 64 + j_;         \
      yrow[go_] = f2bf(accY[nf][q] * bf2f(rr[q * 4 + nf]));                       \
    }                                                                             \
    /* Mc + S update */                                                           \
    bf16x8 af2[2];                                                                \
    _Pragma("unroll") for (int kk = 0; kk < 2; ++kk)                              \
      af2[kk] = *reinterpret_cast<const bf16x8*>(&kIAfA[(w * 2 + kk) * 512 + lane * 8]); \
    f32x4 accM[4];                                                                \
    _Pragma("unroll") for (int nf = 0; nf < 4; ++nf)                              \
      accM[nf] = (f32x4){0.f, 0.f, 0.f, 0.f};                                     \
    _Pragma("unroll") for (int kk = 0; kk < 2; ++kk)                              \
    _Pragma("unroll") for (int nf = 0; nf < 4; ++nf)                              \
      accM[nf] = __builtin_amdgcn_mfma_f32_16x16x32_bf16(af2[kk], vfr[nf * 2 + kk], accM[nf], 0, 0, 0); \
    float aei[4];                                                                 \
    _Pragma("unroll") for (int q = 0; q < 4; ++q) aei[q] = ae[w * 16 + fq * 4 + q]; \
    _Pragma("unroll") for (int nf = 0; nf < 4; ++nf)                              \
    _Pragma("unroll") for (int q = 0; q < 4; ++q)                                 \
      S[nf][q] = aei[q] * (S[nf][q] + accM[nf][q]);                               \
    __syncthreads(); /* all y reads of S0f done */                                \
    {                                                                             \
      const int sb_ = ((((w & 1) * 2 + (fq >> 1)) * 16 + fr) * 8) + (fq & 1) * 4; \
      _Pragma("unroll") for (int nf = 0; nf < 4; ++nf) {                          \
        ushort4 o_;                                                               \
        o_.x = f2bf(S[nf][0]); o_.y = f2bf(S[nf][1]);                             \
        o_.z = f2bf(S[nf][2]); o_.w = f2bf(S[nf][3]);                             \
        *reinterpret_cast<ushort4*>(&S0f[(nf * 2 + (w >> 1)) * 512 + sb_]) = o_;  \
      }                                                                           \
    }                                                                             \
  }

  LOADK(0, kA0, kA1, zA0, zA1);
  LOADV(0, vA);

  for (int c = 0; c < NC; c += 2) {
    STAGE(kA0, kA1, zA0, zA1);
    __syncthreads();  // staging + S0f(prev) visible
    LOADK(c + 1, kB0, kB1, zB0, zB1);
    LOADV(c + 1, vB);
    COMPUTE(c, vA);

    STAGE(kB0, kB1, zB0, zB1);
    __syncthreads();
    LOADK(c + 2, kA0, kA1, zA0, zA1);
    LOADV(c + 2, vA);
    COMPUTE(c + 1, vB);
  }
#undef LOADK
#undef LOADV
#undef STAGE
#undef COMPUTE
}

// ---------------- launch ----------------
extern "C" void kernel_launch(void* const* d_in, const int* in_sizes, int n_in,
                              void* d_out, int out_size, void* d_ws, size_t ws_size,
                              hipStream_t stream) {
  const float* x     = (const float*)d_in[0];
  const float* Wx    = (const float*)d_in[1];
  const float* Ww    = (const float*)d_in[2];
  const float* bw    = (const float*)d_in[3];
  const float* Wk    = (const float*)d_in[4];
  const float* Wv    = (const float*)d_in[5];
  const float* Wr    = (const float*)d_in[6];
  const float* Wo    = (const float*)d_in[7];
  const float* gamma = (const float*)d_in[8];
  const float* beta  = (const float*)d_in[9];
  float* out = (float*)d_out;

  // workspace (bytes), NEED proven rounds 3-8:
  //   xn   [0,          25165824)  bf16 xn
  //   wb   [25165824,   32243712)  6 slots: Wk,Wv,Wr,M,Wo,Ww
  //   WxT  [32243712,   57409536)  head: WxT (dead after M-gemm)
  //   kb   [57409536,   82575360)
  //   vbF  [82575360,  107741184)  v fragment layout per (bh,c)
  //   rb   [107741184, 132907008)
  //   yr   [132907008, 158072832)
  //   zb   [158072832, 183238656)  bf16 z (w-projection pre-activation)
  const size_t NEED = 208404480ull;
  if (ws_size < NEED) {
    zero_out_kernel<<<2048, 256, 0, stream>>>(out, out_size);
    return;
  }

  char* ws = (char*)d_ws;
  ushort* xn  = (ushort*)ws;
  ushort* wb  = (ushort*)(ws + 25165824);
  ushort* WxT = (ushort*)(ws + 32243712);
  ushort* kb  = (ushort*)(ws + 57409536);
  ushort* vbF = (ushort*)(ws + 82575360);
  ushort* rb  = (ushort*)(ws + 107741184);
  ushort* yr  = (ushort*)(ws + 132907008);
  ushort* zb  = (ushort*)(ws + 158072832);

  ushort* WcatB = wb;                 // slots 0..3: Wk, Wv, Wr, M
  ushort* Mb  = wb + 3 * 589824;
  ushort* WoB = wb + 4 * 589824;
  ushort* WwB = wb + 5 * 589824;

  cast5_kernel<<<dim3(576, 5), 256, 0, stream>>>(Wk, Wv, Wr, Wo, Ww, wb);
  transpose_cast_kernel<<<dim3(24, 24), 256, 0, stream>>>(Wx, WxT);
  // composite M = Ww @ Wx
  gemm256<<<dim3(3, 3), 512, 0, stream>>>(WwB, WxT, nullptr, Mb, nullptr, nullptr,
                                          nullptr, 5);
  ln_kernel<<<4096, 256, 0, stream>>>(x, gamma, beta, xn);

  // fused k/v/r/z GEMM (N=3072): k bf16, v frag, r sigmoid bf16, z bf16
  gemm256<<<dim3(64, 12), 512, 0, stream>>>(xn, WcatB, nullptr, kb, vbF, rb, zb, 5);

  scan_fused<<<96, 256, 0, stream>>>(kb, zb, vbF, rb, bw, yr);

  // final GEMM (N=768): fp32 out
  gemm256<<<dim3(64, 3), 512, 0, stream>>>(yr, WoB, out, nullptr, nullptr, nullptr,
                                           nullptr, 0);
}

// Round 10
// 282.619 us; speedup vs baseline: 1.8972x; 1.8972x over previous
//
#include <hip/hip_runtime.h>

#define B_ 8
#define T_ 2048
#define D_ 768
#define H_ 12
#define HS_ 64
#define LN_EPS 1e-5f
#define NC 32   // chunks
#define TC 64   // timesteps per chunk

typedef __attribute__((ext_vector_type(8))) short bf16x8;
typedef __attribute__((ext_vector_type(4))) float f32x4;

__device__ __forceinline__ ushort f2bf(float f) {
  unsigned u = __builtin_bit_cast(unsigned, f);
  unsigned r = (u + 0x7FFFu + ((u >> 16) & 1u)) >> 16;
  return (ushort)r;
}
__device__ __forceinline__ float bf2f(ushort u) {
  return __builtin_bit_cast(float, ((unsigned)u) << 16);
}

// fragment address: element (row t, col i) of a 64x64 tile in MFMA A/B-frag
// layout (m/n = t, k = i). 8 frags x 512 halves.
__device__ __forceinline__ int fragaddr(int t, int i) {
  return ((t >> 4) * 2 + (i >> 5)) * 512 + ((((i >> 3) & 3) * 16) + (t & 15)) * 8 + (i & 7);
}
__device__ __forceinline__ int fragswz(int i) {
  return (((i >> 3) & 3) << 3) ^ (((i >> 5) & 1) << 5);
}

// ---------------- canary ----------------
__global__ __launch_bounds__(256) void zero_out_kernel(float* __restrict__ out, int n) {
  for (int i = blockIdx.x * 256 + threadIdx.x; i < n; i += gridDim.x * 256)
    out[i] = 0.f;
}

// ---------------- weight cast: 5 sources -> slots {0,1,2,4,5} ----------------
__global__ __launch_bounds__(256) void cast5_kernel(
    const float* __restrict__ w0, const float* __restrict__ w1,
    const float* __restrict__ w2, const float* __restrict__ w3,
    const float* __restrict__ w4, ushort* __restrict__ dst) {
  const float* srcs[5] = {w0, w1, w2, w3, w4};
  const int slots[5] = {0, 1, 2, 4, 5};
  const float* src = srcs[blockIdx.y];
  ushort* d = dst + (size_t)slots[blockIdx.y] * 589824;
  int idx = (blockIdx.x * 256 + threadIdx.x) * 4;
  float4 v = *reinterpret_cast<const float4*>(src + idx);
  ushort4 o;
  o.x = f2bf(v.x); o.y = f2bf(v.y); o.z = f2bf(v.z); o.w = f2bf(v.w);
  *reinterpret_cast<ushort4*>(d + idx) = o;
}

// ---------------- transpose-cast: WxT[d][e] = Wx[e][d] ----------------
__global__ __launch_bounds__(256) void transpose_cast_kernel(
    const float* __restrict__ src, ushort* __restrict__ dst) {
  __shared__ ushort tile[32][33];
  const int bx = blockIdx.x * 32;
  const int by = blockIdx.y * 32;
  const int tx = threadIdx.x & 31, ty = threadIdx.x >> 5;
#pragma unroll
  for (int r = 0; r < 32; r += 8)
    tile[ty + r][tx] = f2bf(src[(size_t)(by + ty + r) * 768 + bx + tx]);
  __syncthreads();
#pragma unroll
  for (int r = 0; r < 32; r += 8)
    dst[(size_t)(bx + ty + r) * 768 + by + tx] = tile[tx][ty + r];
}

// ---------------- LayerNorm ----------------
__global__ __launch_bounds__(256) void ln_kernel(
    const float* __restrict__ x, const float* __restrict__ gamma,
    const float* __restrict__ beta, ushort* __restrict__ xn) {
  const int wv = threadIdx.x >> 6;
  const int lane = threadIdx.x & 63;
  const int row = blockIdx.x * 4 + wv;
  const float* xr = x + (size_t)row * D_;
  float4 a[3];
#pragma unroll
  for (int s = 0; s < 3; ++s)
    a[s] = *reinterpret_cast<const float4*>(xr + s * 256 + lane * 4);
  float sum = 0.f;
#pragma unroll
  for (int s = 0; s < 3; ++s) sum += a[s].x + a[s].y + a[s].z + a[s].w;
#pragma unroll
  for (int off = 32; off; off >>= 1) sum += __shfl_xor(sum, off);
  float mu = sum * (1.f / 768.f);
  float vs = 0.f;
#pragma unroll
  for (int s = 0; s < 3; ++s) {
    float dx = a[s].x - mu, dy = a[s].y - mu, dz = a[s].z - mu, dw = a[s].w - mu;
    vs += dx * dx + dy * dy + dz * dz + dw * dw;
  }
#pragma unroll
  for (int off = 32; off; off >>= 1) vs += __shfl_xor(vs, off);
  float rs = rsqrtf(vs * (1.f / 768.f) + LN_EPS);
  ushort* orow = xn + (size_t)row * D_;
#pragma unroll
  for (int s = 0; s < 3; ++s) {
    int col = s * 256 + lane * 4;
    float4 g = *reinterpret_cast<const float4*>(gamma + col);
    float4 bb = *reinterpret_cast<const float4*>(beta + col);
    ushort4 o;
    o.x = f2bf((a[s].x - mu) * rs * g.x + bb.x);
    o.y = f2bf((a[s].y - mu) * rs * g.y + bb.y);
    o.z = f2bf((a[s].z - mu) * rs * g.z + bb.z);
    o.w = f2bf((a[s].w - mu) * rs * g.w + bb.w);
    *reinterpret_cast<ushort4*>(orow + col) = o;
  }
}

// ---------------- 256x256 8-phase bf16 MFMA GEMM (r6/r8-proven schedule) -----
// C[m,n] = sum_k A[m,k]*W[n,k].  K=768. 512 threads = 8 waves (2M x 4N).
// modes: 0 fp32 plain
//        5 cat -> sel0: d0 bf16 | sel1: d1 v FRAG layout | sel2: d2 sigmoid bf16
//                 sel3: d3 bf16 plain (z)
__global__ __launch_bounds__(512, 2) void gemm256(
    const ushort* __restrict__ A, const ushort* __restrict__ W,
    float* __restrict__ Cf,
    ushort* __restrict__ d0, ushort* __restrict__ d1,
    ushort* __restrict__ d2, ushort* __restrict__ d3, int mode) {
  __shared__ __align__(16) ushort lds[65536];  // 128 KiB
  const int tid = threadIdx.x;
  const int wid = tid >> 6;
  const int lane = tid & 63;
  const int wr = wid >> 2, wc = wid & 3;
  const int fr = lane & 15, fq = lane >> 4;
  const int m0 = blockIdx.x * 256, n0 = blockIdx.y * 256;
  const int strow = tid >> 3;
  const int stblk = tid & 7;

  const int RA0 = wr * 8192;
  const int RA1 = 32768 + wr * 8192;
  const int RB0 = 16384 + (wc >> 1) * 8192 + (wc & 1) * 4096;
  const int RB1 = 49152 + (wc >> 1) * 8192 + (wc & 1) * 4096;

  f32x4 acc[8][4];
#pragma unroll
  for (int m = 0; m < 8; ++m)
#pragma unroll
    for (int n = 0; n < 4; ++n) acc[m][n] = (f32x4){0.f, 0.f, 0.f, 0.f};

#define STAGE_HALF(gb, grow0, kk0, roff)                                          \
  {                                                                               \
    _Pragma("unroll") for (int j = 0; j < 2; ++j) {                               \
      const int lr_ = j * 64 + strow;                                             \
      const int bs_ = stblk ^ (lr_ & 7);                                          \
      const ushort* s_ = (gb) + (size_t)((grow0) + lr_) * 768 + (kk0) + bs_ * 8;  \
      __builtin_amdgcn_global_load_lds(                                           \
          (const __attribute__((address_space(1))) void*)s_,                      \
          (__attribute__((address_space(3))) void*)(lds + (roff) + j * 4096 + wid * 512), \
          16, 0, 0);                                                              \
    }                                                                             \
  }

#define LDF(dst, base, rf, kk)                                                    \
  dst = *reinterpret_cast<const bf16x8*>(                                         \
      lds + (base) + ((rf)*16 + fr) * 64 + ((((kk)*4 + fq) ^ (fr & 7)) * 8));

#define MFMA_Q(mb, nb, aa, bb)                                                    \
  __builtin_amdgcn_s_setprio(1);                                                  \
  _Pragma("unroll") for (int m_ = 0; m_ < 4; ++m_)                                \
  _Pragma("unroll") for (int n_ = 0; n_ < 2; ++n_)                                \
  _Pragma("unroll") for (int k_ = 0; k_ < 2; ++k_)                                \
    acc[(mb) + m_][(nb) + n_] = __builtin_amdgcn_mfma_f32_16x16x32_bf16(          \
        aa[m_][k_], bb[n_][k_], acc[(mb) + m_][(nb) + n_], 0, 0, 0);              \
  __builtin_amdgcn_s_setprio(0);

  STAGE_HALF(A, m0, 0, 0);
  STAGE_HALF(A, m0 + 128, 0, 8192);
  STAGE_HALF(W, n0, 0, 16384);
  STAGE_HALF(W, n0 + 128, 0, 24576);
  STAGE_HALF(W, n0, 64, 49152);
  STAGE_HALF(W, n0 + 128, 64, 57344);
  asm volatile("s_waitcnt vmcnt(4)" ::: "memory");
  __builtin_amdgcn_s_barrier();

  bf16x8 aL[4][2], aH[4][2], bL[2][2], bH[2][2];

  for (int i = 0; i < 6; ++i) {
    const int kQ = (2 * i + 1) * 64;
    const int kP2 = (2 * i + 2 <= 11 ? 2 * i + 2 : 11) * 64;
    const int kQ2 = (2 * i + 3 <= 11 ? 2 * i + 3 : 11) * 64;

    STAGE_HALF(A, m0, kQ, 32768);
#pragma unroll
    for (int m = 0; m < 4; ++m) { LDF(aL[m][0], RA0, m, 0); LDF(aL[m][1], RA0, m, 1); }
#pragma unroll
    for (int n = 0; n < 2; ++n) { LDF(bL[n][0], RB0, n, 0); LDF(bL[n][1], RB0, n, 1); }
    __builtin_amdgcn_s_barrier();
    MFMA_Q(0, 0, aL, bL);
    __builtin_amdgcn_s_barrier();

    STAGE_HALF(A, m0 + 128, kQ, 40960);
#pragma unroll
    for (int n = 0; n < 2; ++n) { LDF(bH[n][0], RB0, n + 2, 0); LDF(bH[n][1], RB0, n + 2, 1); }
    __builtin_amdgcn_s_barrier();
    MFMA_Q(0, 2, aL, bH);
    __builtin_amdgcn_s_barrier();

    STAGE_HALF(W, n0, kP2, 16384);
#pragma unroll
    for (int m = 0; m < 4; ++m) { LDF(aH[m][0], RA0, m + 4, 0); LDF(aH[m][1], RA0, m + 4, 1); }
    __builtin_amdgcn_s_barrier();
    MFMA_Q(4, 0, aH, bL);
    __builtin_amdgcn_s_barrier();

    STAGE_HALF(W, n0 + 128, kP2, 24576);
    __builtin_amdgcn_s_barrier();
    MFMA_Q(4, 2, aH, bH);
    asm volatile("s_waitcnt vmcnt(4)" ::: "memory");
    __builtin_amdgcn_s_barrier();

    STAGE_HALF(A, m0, kP2, 0);
#pragma unroll
    for (int m = 0; m < 4; ++m) { LDF(aL[m][0], RA1, m, 0); LDF(aL[m][1], RA1, m, 1); }
#pragma unroll
    for (int n = 0; n < 2; ++n) { LDF(bL[n][0], RB1, n, 0); LDF(bL[n][1], RB1, n, 1); }
    __builtin_amdgcn_s_barrier();
    MFMA_Q(0, 0, aL, bL);
    __builtin_amdgcn_s_barrier();

    STAGE_HALF(A, m0 + 128, kP2, 8192);
#pragma unroll
    for (int n = 0; n < 2; ++n) { LDF(bH[n][0], RB1, n + 2, 0); LDF(bH[n][1], RB1, n + 2, 1); }
    __builtin_amdgcn_s_barrier();
    MFMA_Q(0, 2, aL, bH);
    __builtin_amdgcn_s_barrier();

    STAGE_HALF(W, n0, kQ2, 49152);
#pragma unroll
    for (int m = 0; m < 4; ++m) { LDF(aH[m][0], RA1, m + 4, 0); LDF(aH[m][1], RA1, m + 4, 1); }
    __builtin_amdgcn_s_barrier();
    MFMA_Q(4, 0, aH, bL);
    __builtin_amdgcn_s_barrier();

    STAGE_HALF(W, n0 + 128, kQ2, 57344);
    __builtin_amdgcn_s_barrier();
    MFMA_Q(4, 2, aH, bH);
    asm volatile("s_waitcnt vmcnt(4)" ::: "memory");
    __builtin_amdgcn_s_barrier();
  }

  // ---- epilogue ----
  const int r0 = fq * 4;
  if (mode == 5) {
    const int sel = n0 >= 2304 ? 3 : n0 >= 1536 ? 2 : n0 >= 768 ? 1 : 0;
    const int nb = n0 - sel * 768;
    if (sel == 1) {
#pragma unroll
      for (int mf = 0; mf < 8; ++mf)
#pragma unroll
        for (int nf = 0; nf < 4; ++nf) {
          int gr = m0 + wr * 128 + mf * 16 + r0;
          int gc = nb + wc * 64 + nf * 16 + fr;
          int b = gr >> 11, t = gr & 2047;
          int c = t >> 6, s0 = t & 63;
          int h = gc >> 6, j = gc & 63;
          size_t addr = ((size_t)((b * 12 + h) * 32 + c)) * 4096 +
                        (size_t)(((j >> 4) * 2 + (s0 >> 5)) * 512 +
                                 (((s0 >> 3) & 3) * 16 + (j & 15)) * 8 + (s0 & 7));
          ushort4 o;
          o.x = f2bf(acc[mf][nf][0]); o.y = f2bf(acc[mf][nf][1]);
          o.z = f2bf(acc[mf][nf][2]); o.w = f2bf(acc[mf][nf][3]);
          *reinterpret_cast<ushort4*>(d1 + addr) = o;
        }
    } else {
      ushort* dst = sel == 0 ? d0 : sel == 2 ? d2 : d3;
      const bool sig = (sel == 2);
#pragma unroll
      for (int mf = 0; mf < 8; ++mf)
#pragma unroll
        for (int nf = 0; nf < 4; ++nf) {
          int gr = m0 + wr * 128 + mf * 16 + r0;
          int gc = nb + wc * 64 + nf * 16 + fr;
#pragma unroll
          for (int rr = 0; rr < 4; ++rr) {
            float v = acc[mf][nf][rr];
            if (sig) v = 1.f / (1.f + __expf(-v));
            dst[(size_t)(gr + rr) * 768 + gc] = f2bf(v);
          }
        }
    }
  } else {
#pragma unroll
    for (int mf = 0; mf < 8; ++mf)
#pragma unroll
      for (int nf = 0; nf < 4; ++nf) {
        int gr = m0 + wr * 128 + mf * 16 + r0;
        int gc = n0 + wc * 64 + nf * 16 + fr;
#pragma unroll
        for (int rr = 0; rr < 4; ++rr)
          Cf[(size_t)(gr + rr) * 768 + gc] = acc[mf][nf][rr];
      }
  }
#undef STAGE_HALF
#undef LDF
#undef MFMA_Q
}

// ---------------- fused selective scan: one block per (b,h), S in registers --
// Per chunk: d_t[i]=sigmoid(-(z+bw_h)); a=cumprod(d); kA=k*a, kIA=k/a;
// y = kA.S0f + causal(kA.kIA^T).V ; Mc = kIA^T.V ; S = aend*(S+Mc).
// __launch_bounds__(256,1): grid=96 -> 1 block/CU; full VGPR budget, no spill.
__global__ __launch_bounds__(256, 1) void scan_fused(
    const ushort* __restrict__ kb, const ushort* __restrict__ zb,
    const ushort* __restrict__ vbF, const ushort* __restrict__ rb,
    const float* __restrict__ bwp, ushort* __restrict__ yrow) {
  __shared__ ushort kt[64 * 72];
  __shared__ ushort zt[64 * 72];
  __shared__ ushort kAf[4096];
  __shared__ ushort kIAfB[4096];
  __shared__ ushort kIAfA[4096];
  __shared__ ushort Am[64 * 72];
  __shared__ ushort S0f[4096];
  __shared__ float part[256];
  __shared__ float ae[64];

  const int bh = blockIdx.x;
  const int b = bh / H_, h = bh % H_;
  const int tid = threadIdx.x;
  const int w = tid >> 6, lane = tid & 63;
  const int fr = lane & 15, fq = lane >> 4;
  const int row = tid >> 2, c16 = (tid & 3) * 16;
  const float bwh = bwp[h * 64];
  const int swz = fragswz(lane);

  {
    uint4 z4 = {0, 0, 0, 0};
    *reinterpret_cast<uint4*>(&S0f[tid * 16]) = z4;
    *reinterpret_cast<uint4*>(&S0f[tid * 16 + 8]) = z4;
  }
  f32x4 S[4];
#pragma unroll
  for (int nf = 0; nf < 4; ++nf) S[nf] = (f32x4){0.f, 0.f, 0.f, 0.f};

  uint4 kA0, kA1, zA0, zA1, kB0, kB1, zB0, zB1;
  bf16x8 vA[8], vB[8];

#define LOADK(cc, k0, k1, z0, z1)                                                 \
  {                                                                               \
    int cl_ = (cc) < NC ? (cc) : NC - 1;                                          \
    const ushort* gk_ = kb + ((size_t)(b * T_ + cl_ * TC + row)) * 768 + h * 64 + c16; \
    const ushort* gz_ = zb + ((size_t)(b * T_ + cl_ * TC + row)) * 768 + h * 64 + c16; \
    k0 = *(const uint4*)gk_; k1 = *(const uint4*)(gk_ + 8);                       \
    z0 = *(const uint4*)gz_; z1 = *(const uint4*)(gz_ + 8);                       \
  }

#define LOADV(cc, vfr)                                                            \
  {                                                                               \
    int cl_ = (cc) < NC ? (cc) : NC - 1;                                          \
    const ushort* vch_ = vbF + ((size_t)bh * NC + cl_) * 4096;                    \
    _Pragma("unroll") for (int f = 0; f < 8; ++f)                                 \
      vfr[f] = *reinterpret_cast<const bf16x8*>(vch_ + f * 512 + lane * 8);       \
  }

#define STAGE(k0, k1, z0, z1)                                                     \
  {                                                                               \
    *reinterpret_cast<uint4*>(&kt[row * 72 + c16]) = k0;                          \
    *reinterpret_cast<uint4*>(&kt[row * 72 + c16 + 8]) = k1;                      \
    *reinterpret_cast<uint4*>(&zt[row * 72 + c16]) = z0;                          \
    *reinterpret_cast<uint4*>(&zt[row * 72 + c16 + 8]) = z1;                      \
  }

#define COMPUTE(cc, vfr)                                                          \
  {                                                                               \
    const int c_ = (cc);                                                          \
    ushort rr[16];                                                                \
    {                                                                             \
      const ushort* rrow_ = rb + ((size_t)(b * T_ + c_ * TC)) * 768 + h * 64;     \
      _Pragma("unroll") for (int tp = 0; tp < 4; ++tp)                            \
      _Pragma("unroll") for (int nf = 0; nf < 4; ++nf)                            \
        rr[tp * 4 + nf] = rrow_[(size_t)(w * 16 + fq * 4 + tp) * 768 + nf * 16 + fr]; \
    }                                                                             \
    float dreg[16];                                                               \
    float p_ = 1.f;                                                               \
    _Pragma("unroll") for (int tt = 0; tt < 16; ++tt) {                           \
      float z_ = bf2f(zt[(w * 16 + tt) * 72 + lane]);                             \
      float d_ = 1.f / (1.f + __expf(z_ + bwh));                                  \
      dreg[tt] = d_;                                                              \
      p_ *= d_;                                                                   \
    }                                                                             \
    part[w * 64 + lane] = p_;                                                     \
    __syncthreads();                                                              \
    float a_ = 1.f;                                                               \
    for (int w2 = 0; w2 < w; ++w2) a_ *= part[w2 * 64 + lane];                    \
    if (w == 0)                                                                   \
      ae[lane] = part[lane] * part[64 + lane] * part[128 + lane] * part[192 + lane]; \
    _Pragma("unroll") for (int tt = 0; tt < 16; ++tt) {                           \
      int t_ = w * 16 + tt;                                                       \
      float k_ = bf2f(kt[t_ * 72 + lane]);                                        \
      a_ *= dreg[tt];                                                             \
      int ad_ = fragaddr(t_, lane) ^ swz;                                         \
      kAf[ad_] = f2bf(k_ * a_);                                                   \
      ushort ki_ = f2bf(k_ / a_);                                                 \
      kIAfB[ad_] = ki_;                                                           \
      kIAfA[fragaddr(lane, t_)] = ki_;                                            \
    }                                                                             \
    __syncthreads();                                                              \
    bf16x8 af[2];                                                                 \
    _Pragma("unroll") for (int kk = 0; kk < 2; ++kk) {                            \
      int ra_ = ((w * 2 + kk) * 512 + lane * 8) ^ (((lane >> 4) << 3) ^ (kk << 5)); \
      af[kk] = *reinterpret_cast<const bf16x8*>(&kAf[ra_]);                       \
    }                                                                             \
    {                                                                             \
      f32x4 accA[4];                                                              \
      _Pragma("unroll") for (int nf = 0; nf < 4; ++nf)                            \
        accA[nf] = (f32x4){0.f, 0.f, 0.f, 0.f};                                   \
      _Pragma("unroll") for (int kk = 0; kk < 2; ++kk)                            \
      _Pragma("unroll") for (int nf = 0; nf < 4; ++nf) {                          \
        int rb8_ = ((nf * 2 + kk) * 512 + lane * 8) ^ (((lane >> 4) << 3) ^ (kk << 5)); \
        bf16x8 b8_ = *reinterpret_cast<const bf16x8*>(&kIAfB[rb8_]);              \
        accA[nf] = __builtin_amdgcn_mfma_f32_16x16x32_bf16(af[kk], b8_, accA[nf], 0, 0, 0); \
      }                                                                           \
      _Pragma("unroll") for (int nf = 0; nf < 4; ++nf)                            \
      _Pragma("unroll") for (int q = 0; q < 4; ++q) {                             \
        int t_ = w * 16 + fq * 4 + q;                                             \
        int s_ = nf * 16 + fr;                                                    \
        Am[t_ * 72 + s_] = f2bf((s_ <= t_) ? accA[nf][q] : 0.f);                  \
      }                                                                           \
    }                                                                             \
    __syncthreads();                                                              \
    f32x4 accY[4];                                                                \
    _Pragma("unroll") for (int nf = 0; nf < 4; ++nf)                              \
      accY[nf] = (f32x4){0.f, 0.f, 0.f, 0.f};                                     \
    _Pragma("unroll") for (int kk = 0; kk < 2; ++kk)                              \
    _Pragma("unroll") for (int nf = 0; nf < 4; ++nf) {                            \
      bf16x8 b8_ = *reinterpret_cast<const bf16x8*>(&S0f[(nf * 2 + kk) * 512 + lane * 8]); \
      accY[nf] = __builtin_amdgcn_mfma_f32_16x16x32_bf16(af[kk], b8_, accY[nf], 0, 0, 0); \
    }                                                                             \
    _Pragma("unroll") for (int kk = 0; kk < 2; ++kk) {                            \
      bf16x8 am8_ = *reinterpret_cast<const bf16x8*>(&Am[(w * 16 + fr) * 72 + kk * 32 + fq * 8]); \
      _Pragma("unroll") for (int nf = 0; nf < 4; ++nf)                            \
        accY[nf] = __builtin_amdgcn_mfma_f32_16x16x32_bf16(am8_, vfr[nf * 2 + kk], accY[nf], 0, 0, 0); \
    }                                                                             \
    _Pragma("unroll") for (int nf = 0; nf < 4; ++nf)                              \
    _Pragma("unroll") for (int q = 0; q < 4; ++q) {                               \
      int t_ = w * 16 + fq * 4 + q;                                               \
      int j_ = nf * 16 + fr;                                                      \
      size_t go_ = ((size_t)(b * T_ + c_ * TC + t_)) * 768 + h * 64 + j_;         \
      yrow[go_] = f2bf(accY[nf][q] * bf2f(rr[q * 4 + nf]));                       \
    }                                                                             \
    bf16x8 af2[2];                                                                \
    _Pragma("unroll") for (int kk = 0; kk < 2; ++kk)                              \
      af2[kk] = *reinterpret_cast<const bf16x8*>(&kIAfA[(w * 2 + kk) * 512 + lane * 8]); \
    f32x4 accM[4];                                                                \
    _Pragma("unroll") for (int nf = 0; nf < 4; ++nf)                              \
      accM[nf] = (f32x4){0.f, 0.f, 0.f, 0.f};                                     \
    _Pragma("unroll") for (int kk = 0; kk < 2; ++kk)                              \
    _Pragma("unroll") for (int nf = 0; nf < 4; ++nf)                              \
      accM[nf] = __builtin_amdgcn_mfma_f32_16x16x32_bf16(af2[kk], vfr[nf * 2 + kk], accM[nf], 0, 0, 0); \
    float aei[4];                                                                 \
    _Pragma("unroll") for (int q = 0; q < 4; ++q) aei[q] = ae[w * 16 + fq * 4 + q]; \
    _Pragma("unroll") for (int nf = 0; nf < 4; ++nf)                              \
    _Pragma("unroll") for (int q = 0; q < 4; ++q)                                 \
      S[nf][q] = aei[q] * (S[nf][q] + accM[nf][q]);                               \
    __syncthreads(); /* all y reads of S0f done */                                \
    {                                                                             \
      const int sb_ = ((((w & 1) * 2 + (fq >> 1)) * 16 + fr) * 8) + (fq & 1) * 4; \
      _Pragma("unroll") for (int nf = 0; nf < 4; ++nf) {                          \
        ushort4 o_;                                                               \
        o_.x = f2bf(S[nf][0]); o_.y = f2bf(S[nf][1]);                             \
        o_.z = f2bf(S[nf][2]); o_.w = f2bf(S[nf][3]);                             \
        *reinterpret_cast<ushort4*>(&S0f[(nf * 2 + (w >> 1)) * 512 + sb_]) = o_;  \
      }                                                                           \
    }                                                                             \
  }

  LOADK(0, kA0, kA1, zA0, zA1);
  LOADV(0, vA);

  for (int c = 0; c < NC; c += 2) {
    STAGE(kA0, kA1, zA0, zA1);
    __syncthreads();  // staging + S0f(prev) visible
    LOADK(c + 1, kB0, kB1, zB0, zB1);
    LOADV(c + 1, vB);
    COMPUTE(c, vA);

    STAGE(kB0, kB1, zB0, zB1);
    __syncthreads();
    LOADK(c + 2, kA0, kA1, zA0, zA1);
    LOADV(c + 2, vA);
    COMPUTE(c + 1, vB);
  }
#undef LOADK
#undef LOADV
#undef STAGE
#undef COMPUTE
}

// ---------------- launch ----------------
extern "C" void kernel_launch(void* const* d_in, const int* in_sizes, int n_in,
                              void* d_out, int out_size, void* d_ws, size_t ws_size,
                              hipStream_t stream) {
  const float* x     = (const float*)d_in[0];
  const float* Wx    = (const float*)d_in[1];
  const float* Ww    = (const float*)d_in[2];
  const float* bw    = (const float*)d_in[3];
  const float* Wk    = (const float*)d_in[4];
  const float* Wv    = (const float*)d_in[5];
  const float* Wr    = (const float*)d_in[6];
  const float* Wo    = (const float*)d_in[7];
  const float* gamma = (const float*)d_in[8];
  const float* beta  = (const float*)d_in[9];
  float* out = (float*)d_out;

  // workspace (bytes), NEED proven rounds 3-9:
  //   xn   [0,          25165824)  bf16 xn
  //   wb   [25165824,   32243712)  6 slots: Wk,Wv,Wr,M,Wo,Ww
  //   WxT  [32243712,   57409536)  head: WxT (dead after M-gemm)
  //   kb   [57409536,   82575360)
  //   vbF  [82575360,  107741184)  v fragment layout per (bh,c)
  //   rb   [107741184, 132907008)
  //   yr   [132907008, 158072832)
  //   zb   [158072832, 183238656)  bf16 z (w-projection pre-activation)
  const size_t NEED = 208404480ull;
  if (ws_size < NEED) {
    zero_out_kernel<<<2048, 256, 0, stream>>>(out, out_size);
    return;
  }

  char* ws = (char*)d_ws;
  ushort* xn  = (ushort*)ws;
  ushort* wb  = (ushort*)(ws + 25165824);
  ushort* WxT = (ushort*)(ws + 32243712);
  ushort* kb  = (ushort*)(ws + 57409536);
  ushort* vbF = (ushort*)(ws + 82575360);
  ushort* rb  = (ushort*)(ws + 107741184);
  ushort* yr  = (ushort*)(ws + 132907008);
  ushort* zb  = (ushort*)(ws + 158072832);

  ushort* WcatB = wb;                 // slots 0..3: Wk, Wv, Wr, M
  ushort* Mb  = wb + 3 * 589824;
  ushort* WoB = wb + 4 * 589824;
  ushort* WwB = wb + 5 * 589824;

  cast5_kernel<<<dim3(576, 5), 256, 0, stream>>>(Wk, Wv, Wr, Wo, Ww, wb);
  transpose_cast_kernel<<<dim3(24, 24), 256, 0, stream>>>(Wx, WxT);
  // composite M = Ww @ Wx
  gemm256<<<dim3(3, 3), 512, 0, stream>>>(WwB, WxT, nullptr, Mb, nullptr, nullptr,
                                          nullptr, 5);
  ln_kernel<<<4096, 256, 0, stream>>>(x, gamma, beta, xn);

  // fused k/v/r/z GEMM (N=3072): k bf16, v frag, r sigmoid bf16, z bf16
  gemm256<<<dim3(64, 12), 512, 0, stream>>>(xn, WcatB, nullptr, kb, vbF, rb, zb, 5);

  scan_fused<<<96, 256, 0, stream>>>(kb, zb, vbF, rb, bw, yr);

  // final GEMM (N=768): fp32 out
  gemm256<<<dim3(64, 3), 512, 0, stream>>>(yr, WoB, out, nullptr, nullptr, nullptr,
                                           nullptr, 0);
}

// Round 11
// 241.710 us; speedup vs baseline: 2.2182x; 1.1692x over previous
//
#include <hip/hip_runtime.h>

#define B_ 8
#define T_ 2048
#define D_ 768
#define H_ 12
#define HS_ 64
#define LN_EPS 1e-5f
#define NC 32   // chunks
#define TC 64   // timesteps per chunk

typedef __attribute__((ext_vector_type(8))) short bf16x8;
typedef __attribute__((ext_vector_type(4))) float f32x4;

__device__ __forceinline__ ushort f2bf(float f) {
  unsigned u = __builtin_bit_cast(unsigned, f);
  unsigned r = (u + 0x7FFFu + ((u >> 16) & 1u)) >> 16;
  return (ushort)r;
}
__device__ __forceinline__ float bf2f(ushort u) {
  return __builtin_bit_cast(float, ((unsigned)u) << 16);
}

// fragment address: element (row t, col i) of a 64x64 tile in MFMA A/B-frag
// layout (m/n = t, k = i). 8 frags x 512 halves.
__device__ __forceinline__ int fragaddr(int t, int i) {
  return ((t >> 4) * 2 + (i >> 5)) * 512 + ((((i >> 3) & 3) * 16) + (t & 15)) * 8 + (i & 7);
}
__device__ __forceinline__ int fragswz(int i) {
  return (((i >> 3) & 3) << 3) ^ (((i >> 5) & 1) << 5);
}

// ---------------- canary ----------------
__global__ __launch_bounds__(256) void zero_out_kernel(float* __restrict__ out, int n) {
  for (int i = blockIdx.x * 256 + threadIdx.x; i < n; i += gridDim.x * 256)
    out[i] = 0.f;
}

// ---------------- weight cast: 5 sources -> slots {0,1,2,4,5} ----------------
__global__ __launch_bounds__(256) void cast5_kernel(
    const float* __restrict__ w0, const float* __restrict__ w1,
    const float* __restrict__ w2, const float* __restrict__ w3,
    const float* __restrict__ w4, ushort* __restrict__ dst) {
  const float* srcs[5] = {w0, w1, w2, w3, w4};
  const int slots[5] = {0, 1, 2, 4, 5};
  const float* src = srcs[blockIdx.y];
  ushort* d = dst + (size_t)slots[blockIdx.y] * 589824;
  int idx = (blockIdx.x * 256 + threadIdx.x) * 4;
  float4 v = *reinterpret_cast<const float4*>(src + idx);
  ushort4 o;
  o.x = f2bf(v.x); o.y = f2bf(v.y); o.z = f2bf(v.z); o.w = f2bf(v.w);
  *reinterpret_cast<ushort4*>(d + idx) = o;
}

// ---------------- transpose-cast: WxT[d][e] = Wx[e][d] ----------------
__global__ __launch_bounds__(256) void transpose_cast_kernel(
    const float* __restrict__ src, ushort* __restrict__ dst) {
  __shared__ ushort tile[32][33];
  const int bx = blockIdx.x * 32;
  const int by = blockIdx.y * 32;
  const int tx = threadIdx.x & 31, ty = threadIdx.x >> 5;
#pragma unroll
  for (int r = 0; r < 32; r += 8)
    tile[ty + r][tx] = f2bf(src[(size_t)(by + ty + r) * 768 + bx + tx]);
  __syncthreads();
#pragma unroll
  for (int r = 0; r < 32; r += 8)
    dst[(size_t)(bx + ty + r) * 768 + by + tx] = tile[tx][ty + r];
}

// ---------------- LayerNorm ----------------
__global__ __launch_bounds__(256) void ln_kernel(
    const float* __restrict__ x, const float* __restrict__ gamma,
    const float* __restrict__ beta, ushort* __restrict__ xn) {
  const int wv = threadIdx.x >> 6;
  const int lane = threadIdx.x & 63;
  const int row = blockIdx.x * 4 + wv;
  const float* xr = x + (size_t)row * D_;
  float4 a[3];
#pragma unroll
  for (int s = 0; s < 3; ++s)
    a[s] = *reinterpret_cast<const float4*>(xr + s * 256 + lane * 4);
  float sum = 0.f;
#pragma unroll
  for (int s = 0; s < 3; ++s) sum += a[s].x + a[s].y + a[s].z + a[s].w;
#pragma unroll
  for (int off = 32; off; off >>= 1) sum += __shfl_xor(sum, off);
  float mu = sum * (1.f / 768.f);
  float vs = 0.f;
#pragma unroll
  for (int s = 0; s < 3; ++s) {
    float dx = a[s].x - mu, dy = a[s].y - mu, dz = a[s].z - mu, dw = a[s].w - mu;
    vs += dx * dx + dy * dy + dz * dz + dw * dw;
  }
#pragma unroll
  for (int off = 32; off; off >>= 1) vs += __shfl_xor(vs, off);
  float rs = rsqrtf(vs * (1.f / 768.f) + LN_EPS);
  ushort* orow = xn + (size_t)row * D_;
#pragma unroll
  for (int s = 0; s < 3; ++s) {
    int col = s * 256 + lane * 4;
    float4 g = *reinterpret_cast<const float4*>(gamma + col);
    float4 bb = *reinterpret_cast<const float4*>(beta + col);
    ushort4 o;
    o.x = f2bf((a[s].x - mu) * rs * g.x + bb.x);
    o.y = f2bf((a[s].y - mu) * rs * g.y + bb.y);
    o.z = f2bf((a[s].z - mu) * rs * g.z + bb.z);
    o.w = f2bf((a[s].w - mu) * rs * g.w + bb.w);
    *reinterpret_cast<ushort4*>(orow + col) = o;
  }
}

// ---------------- 256x256 8-phase bf16 MFMA GEMM (r6/r8-proven schedule) -----
// C[m,n] = sum_k A[m,k]*W[n,k].  K=768. 512 threads = 8 waves (2M x 4N).
// modes: 0 fp32 plain
//        5 cat -> sel0: d0 bf16 | sel1: d1 v FRAG layout | sel2: d2 sigmoid bf16
//                 sel3: d3 bf16 plain (z)
__global__ __launch_bounds__(512, 2) void gemm256(
    const ushort* __restrict__ A, const ushort* __restrict__ W,
    float* __restrict__ Cf,
    ushort* __restrict__ d0, ushort* __restrict__ d1,
    ushort* __restrict__ d2, ushort* __restrict__ d3, int mode) {
  __shared__ __align__(16) ushort lds[65536];  // 128 KiB
  const int tid = threadIdx.x;
  const int wid = tid >> 6;
  const int lane = tid & 63;
  const int wr = wid >> 2, wc = wid & 3;
  const int fr = lane & 15, fq = lane >> 4;
  const int m0 = blockIdx.x * 256, n0 = blockIdx.y * 256;
  const int strow = tid >> 3;
  const int stblk = tid & 7;

  const int RA0 = wr * 8192;
  const int RA1 = 32768 + wr * 8192;
  const int RB0 = 16384 + (wc >> 1) * 8192 + (wc & 1) * 4096;
  const int RB1 = 49152 + (wc >> 1) * 8192 + (wc & 1) * 4096;

  f32x4 acc[8][4];
#pragma unroll
  for (int m = 0; m < 8; ++m)
#pragma unroll
    for (int n = 0; n < 4; ++n) acc[m][n] = (f32x4){0.f, 0.f, 0.f, 0.f};

#define STAGE_HALF(gb, grow0, kk0, roff)                                          \
  {                                                                               \
    _Pragma("unroll") for (int j = 0; j < 2; ++j) {                               \
      const int lr_ = j * 64 + strow;                                             \
      const int bs_ = stblk ^ (lr_ & 7);                                          \
      const ushort* s_ = (gb) + (size_t)((grow0) + lr_) * 768 + (kk0) + bs_ * 8;  \
      __builtin_amdgcn_global_load_lds(                                           \
          (const __attribute__((address_space(1))) void*)s_,                      \
          (__attribute__((address_space(3))) void*)(lds + (roff) + j * 4096 + wid * 512), \
          16, 0, 0);                                                              \
    }                                                                             \
  }

#define LDF(dst, base, rf, kk)                                                    \
  dst = *reinterpret_cast<const bf16x8*>(                                         \
      lds + (base) + ((rf)*16 + fr) * 64 + ((((kk)*4 + fq) ^ (fr & 7)) * 8));

#define MFMA_Q(mb, nb, aa, bb)                                                    \
  __builtin_amdgcn_s_setprio(1);                                                  \
  _Pragma("unroll") for (int m_ = 0; m_ < 4; ++m_)                                \
  _Pragma("unroll") for (int n_ = 0; n_ < 2; ++n_)                                \
  _Pragma("unroll") for (int k_ = 0; k_ < 2; ++k_)                                \
    acc[(mb) + m_][(nb) + n_] = __builtin_amdgcn_mfma_f32_16x16x32_bf16(          \
        aa[m_][k_], bb[n_][k_], acc[(mb) + m_][(nb) + n_], 0, 0, 0);              \
  __builtin_amdgcn_s_setprio(0);

  STAGE_HALF(A, m0, 0, 0);
  STAGE_HALF(A, m0 + 128, 0, 8192);
  STAGE_HALF(W, n0, 0, 16384);
  STAGE_HALF(W, n0 + 128, 0, 24576);
  STAGE_HALF(W, n0, 64, 49152);
  STAGE_HALF(W, n0 + 128, 64, 57344);
  asm volatile("s_waitcnt vmcnt(4)" ::: "memory");
  __builtin_amdgcn_s_barrier();

  bf16x8 aL[4][2], aH[4][2], bL[2][2], bH[2][2];

  for (int i = 0; i < 6; ++i) {
    const int kQ = (2 * i + 1) * 64;
    const int kP2 = (2 * i + 2 <= 11 ? 2 * i + 2 : 11) * 64;
    const int kQ2 = (2 * i + 3 <= 11 ? 2 * i + 3 : 11) * 64;

    STAGE_HALF(A, m0, kQ, 32768);
#pragma unroll
    for (int m = 0; m < 4; ++m) { LDF(aL[m][0], RA0, m, 0); LDF(aL[m][1], RA0, m, 1); }
#pragma unroll
    for (int n = 0; n < 2; ++n) { LDF(bL[n][0], RB0, n, 0); LDF(bL[n][1], RB0, n, 1); }
    __builtin_amdgcn_s_barrier();
    MFMA_Q(0, 0, aL, bL);
    __builtin_amdgcn_s_barrier();

    STAGE_HALF(A, m0 + 128, kQ, 40960);
#pragma unroll
    for (int n = 0; n < 2; ++n) { LDF(bH[n][0], RB0, n + 2, 0); LDF(bH[n][1], RB0, n + 2, 1); }
    __builtin_amdgcn_s_barrier();
    MFMA_Q(0, 2, aL, bH);
    __builtin_amdgcn_s_barrier();

    STAGE_HALF(W, n0, kP2, 16384);
#pragma unroll
    for (int m = 0; m < 4; ++m) { LDF(aH[m][0], RA0, m + 4, 0); LDF(aH[m][1], RA0, m + 4, 1); }
    __builtin_amdgcn_s_barrier();
    MFMA_Q(4, 0, aH, bL);
    __builtin_amdgcn_s_barrier();

    STAGE_HALF(W, n0 + 128, kP2, 24576);
    __builtin_amdgcn_s_barrier();
    MFMA_Q(4, 2, aH, bH);
    asm volatile("s_waitcnt vmcnt(4)" ::: "memory");
    __builtin_amdgcn_s_barrier();

    STAGE_HALF(A, m0, kP2, 0);
#pragma unroll
    for (int m = 0; m < 4; ++m) { LDF(aL[m][0], RA1, m, 0); LDF(aL[m][1], RA1, m, 1); }
#pragma unroll
    for (int n = 0; n < 2; ++n) { LDF(bL[n][0], RB1, n, 0); LDF(bL[n][1], RB1, n, 1); }
    __builtin_amdgcn_s_barrier();
    MFMA_Q(0, 0, aL, bL);
    __builtin_amdgcn_s_barrier();

    STAGE_HALF(A, m0 + 128, kP2, 8192);
#pragma unroll
    for (int n = 0; n < 2; ++n) { LDF(bH[n][0], RB1, n + 2, 0); LDF(bH[n][1], RB1, n + 2, 1); }
    __builtin_amdgcn_s_barrier();
    MFMA_Q(0, 2, aL, bH);
    __builtin_amdgcn_s_barrier();

    STAGE_HALF(W, n0, kQ2, 49152);
#pragma unroll
    for (int m = 0; m < 4; ++m) { LDF(aH[m][0], RA1, m + 4, 0); LDF(aH[m][1], RA1, m + 4, 1); }
    __builtin_amdgcn_s_barrier();
    MFMA_Q(4, 0, aH, bL);
    __builtin_amdgcn_s_barrier();

    STAGE_HALF(W, n0 + 128, kQ2, 57344);
    __builtin_amdgcn_s_barrier();
    MFMA_Q(4, 2, aH, bH);
    asm volatile("s_waitcnt vmcnt(4)" ::: "memory");
    __builtin_amdgcn_s_barrier();
  }

  // ---- epilogue ----
  const int r0 = fq * 4;
  if (mode == 5) {
    const int sel = n0 >= 2304 ? 3 : n0 >= 1536 ? 2 : n0 >= 768 ? 1 : 0;
    const int nb = n0 - sel * 768;
    if (sel == 1) {
#pragma unroll
      for (int mf = 0; mf < 8; ++mf)
#pragma unroll
        for (int nf = 0; nf < 4; ++nf) {
          int gr = m0 + wr * 128 + mf * 16 + r0;
          int gc = nb + wc * 64 + nf * 16 + fr;
          int b = gr >> 11, t = gr & 2047;
          int c = t >> 6, s0 = t & 63;
          int h = gc >> 6, j = gc & 63;
          size_t addr = ((size_t)((b * 12 + h) * 32 + c)) * 4096 +
                        (size_t)(((j >> 4) * 2 + (s0 >> 5)) * 512 +
                                 (((s0 >> 3) & 3) * 16 + (j & 15)) * 8 + (s0 & 7));
          ushort4 o;
          o.x = f2bf(acc[mf][nf][0]); o.y = f2bf(acc[mf][nf][1]);
          o.z = f2bf(acc[mf][nf][2]); o.w = f2bf(acc[mf][nf][3]);
          *reinterpret_cast<ushort4*>(d1 + addr) = o;
        }
    } else {
      ushort* dst = sel == 0 ? d0 : sel == 2 ? d2 : d3;
      const bool sig = (sel == 2);
#pragma unroll
      for (int mf = 0; mf < 8; ++mf)
#pragma unroll
        for (int nf = 0; nf < 4; ++nf) {
          int gr = m0 + wr * 128 + mf * 16 + r0;
          int gc = nb + wc * 64 + nf * 16 + fr;
#pragma unroll
          for (int rr = 0; rr < 4; ++rr) {
            float v = acc[mf][nf][rr];
            if (sig) v = 1.f / (1.f + __expf(-v));
            dst[(size_t)(gr + rr) * 768 + gc] = f2bf(v);
          }
        }
    }
  } else {
#pragma unroll
    for (int mf = 0; mf < 8; ++mf)
#pragma unroll
      for (int nf = 0; nf < 4; ++nf) {
        int gr = m0 + wr * 128 + mf * 16 + r0;
        int gc = n0 + wc * 64 + nf * 16 + fr;
#pragma unroll
        for (int rr = 0; rr < 4; ++rr)
          Cf[(size_t)(gr + rr) * 768 + gc] = acc[mf][nf][rr];
      }
  }
#undef STAGE_HALF
#undef LDF
#undef MFMA_Q
}

// ---------------- scan P: per (bh,c): cumprod + Mc = kIA^T V (parallel) ------
__global__ __launch_bounds__(256) void scan_mc3(
    const ushort* __restrict__ kb, const ushort* __restrict__ zb,
    const ushort* __restrict__ vbF, const float* __restrict__ bwp,
    ushort* __restrict__ McT, float* __restrict__ aend) {
  __shared__ ushort kt[64 * 72];
  __shared__ ushort zt[64 * 72];
  __shared__ ushort kIAfA[4096];
  __shared__ float part[256];
  const int bh = blockIdx.x, c = blockIdx.y;
  const int b = bh / H_, h = bh % H_;
  const int tid = threadIdx.x;
  const int w = tid >> 6, lane = tid & 63;
  const int fr = lane & 15, fq = lane >> 4;
  const int row = tid >> 2, c16 = (tid & 3) * 16;
  const float bwh = bwp[h * 64];

  {
    const ushort* gk = kb + ((size_t)(b * T_ + c * TC + row)) * 768 + h * 64 + c16;
    const ushort* gz = zb + ((size_t)(b * T_ + c * TC + row)) * 768 + h * 64 + c16;
    uint4 k0 = *(const uint4*)gk, k1 = *(const uint4*)(gk + 8);
    uint4 z0 = *(const uint4*)gz, z1 = *(const uint4*)(gz + 8);
    *reinterpret_cast<uint4*>(&kt[row * 72 + c16]) = k0;
    *reinterpret_cast<uint4*>(&kt[row * 72 + c16 + 8]) = k1;
    *reinterpret_cast<uint4*>(&zt[row * 72 + c16]) = z0;
    *reinterpret_cast<uint4*>(&zt[row * 72 + c16 + 8]) = z1;
  }
  bf16x8 vfr[8];
  {
    const ushort* vch = vbF + ((size_t)bh * NC + c) * 4096;
#pragma unroll
    for (int f = 0; f < 8; ++f)
      vfr[f] = *reinterpret_cast<const bf16x8*>(vch + f * 512 + lane * 8);
  }
  __syncthreads();
  float dreg[16];
  float p = 1.f;
#pragma unroll
  for (int tt = 0; tt < 16; ++tt) {
    float z = bf2f(zt[(w * 16 + tt) * 72 + lane]);
    float d = 1.f / (1.f + __expf(z + bwh));
    dreg[tt] = d;
    p *= d;
  }
  part[w * 64 + lane] = p;
  __syncthreads();
  float a = 1.f;
  for (int w2 = 0; w2 < w; ++w2) a *= part[w2 * 64 + lane];
  if (w == 0)
    aend[((size_t)bh * NC + c) * 64 + lane] =
        part[lane] * part[64 + lane] * part[128 + lane] * part[192 + lane];
#pragma unroll
  for (int tt = 0; tt < 16; ++tt) {
    int t = w * 16 + tt;
    float k = bf2f(kt[t * 72 + lane]);
    a *= dreg[tt];
    kIAfA[fragaddr(lane, t)] = f2bf(k / a);  // A-frag (m=i, k=s)
  }
  __syncthreads();

  bf16x8 af2[2];
#pragma unroll
  for (int kk = 0; kk < 2; ++kk)
    af2[kk] = *reinterpret_cast<const bf16x8*>(&kIAfA[(w * 2 + kk) * 512 + lane * 8]);
  f32x4 accM[4];
#pragma unroll
  for (int nf = 0; nf < 4; ++nf) accM[nf] = (f32x4){0.f, 0.f, 0.f, 0.f};
#pragma unroll
  for (int kk = 0; kk < 2; ++kk)
#pragma unroll
    for (int nf = 0; nf < 4; ++nf)
      accM[nf] = __builtin_amdgcn_mfma_f32_16x16x32_bf16(af2[kk], vfr[nf * 2 + kk], accM[nf], 0, 0, 0);
  ushort* mch = McT + ((size_t)bh * NC + c) * 4096;
#pragma unroll
  for (int nf = 0; nf < 4; ++nf) {
    ushort4 o;
    o.x = f2bf(accM[nf][0]); o.y = f2bf(accM[nf][1]);
    o.z = f2bf(accM[nf][2]); o.w = f2bf(accM[nf][3]);
    *reinterpret_cast<ushort4*>(&mch[(nf * 16 + fr) * 64 + w * 16 + fq * 4]) = o;
  }
}

// ---------------- scan C: chain with register prefetch (96 blocks) -----------
// S0_{c+1} = aend_c * (S0_c + Mc_c); S0F in B-frag layout (n=j, k=i).
__global__ __launch_bounds__(256) void scan_chain3(
    const ushort* __restrict__ McT, const float* __restrict__ aend,
    ushort* __restrict__ S0F) {
  const int bh = blockIdx.x;
  const int j = threadIdx.x >> 2, i0 = (threadIdx.x & 3) * 16;
  const int fbase = ((j >> 4) * 2 + (i0 >> 5)) * 512 + (((i0 >> 3) & 3) * 16 + (j & 15)) * 8;
  float S[16];
#pragma unroll
  for (int p = 0; p < 16; ++p) S[p] = 0.f;

  const ushort* mch0 = McT + ((size_t)bh * NC) * 4096 + j * 64 + i0;
  const float* aep0 = aend + ((size_t)bh * NC) * 64 + i0;
  bf16x8 m0 = *reinterpret_cast<const bf16x8*>(mch0);
  bf16x8 m1 = *reinterpret_cast<const bf16x8*>(mch0 + 8);
  float4 a0 = *(const float4*)(aep0);
  float4 a1 = *(const float4*)(aep0 + 4);
  float4 a2 = *(const float4*)(aep0 + 8);
  float4 a3 = *(const float4*)(aep0 + 12);

  for (int c = 0; c < NC; ++c) {
    // prefetch next (clamped)
    int cn = c + 1 < NC ? c + 1 : NC - 1;
    const ushort* mchn = McT + ((size_t)bh * NC + cn) * 4096 + j * 64 + i0;
    const float* aepn = aend + ((size_t)bh * NC + cn) * 64 + i0;
    bf16x8 n0 = *reinterpret_cast<const bf16x8*>(mchn);
    bf16x8 n1 = *reinterpret_cast<const bf16x8*>(mchn + 8);
    float4 b0 = *(const float4*)(aepn);
    float4 b1 = *(const float4*)(aepn + 4);
    float4 b2 = *(const float4*)(aepn + 8);
    float4 b3 = *(const float4*)(aepn + 12);

    // emit S0F for chunk c (state BEFORE update)
    ushort* s0 = S0F + ((size_t)bh * NC + c) * 4096 + fbase;
    ushort4 o0, o1, o2, o3;
    o0.x = f2bf(S[0]); o0.y = f2bf(S[1]); o0.z = f2bf(S[2]); o0.w = f2bf(S[3]);
    o1.x = f2bf(S[4]); o1.y = f2bf(S[5]); o1.z = f2bf(S[6]); o1.w = f2bf(S[7]);
    o2.x = f2bf(S[8]); o2.y = f2bf(S[9]); o2.z = f2bf(S[10]); o2.w = f2bf(S[11]);
    o3.x = f2bf(S[12]); o3.y = f2bf(S[13]); o3.z = f2bf(S[14]); o3.w = f2bf(S[15]);
    *reinterpret_cast<ushort4*>(s0) = o0;
    *reinterpret_cast<ushort4*>(s0 + 4) = o1;
    *reinterpret_cast<ushort4*>(s0 + 128) = o2;
    *reinterpret_cast<ushort4*>(s0 + 132) = o3;

    // update S with current m/a
    float av[16];
    av[0] = a0.x; av[1] = a0.y; av[2] = a0.z; av[3] = a0.w;
    av[4] = a1.x; av[5] = a1.y; av[6] = a1.z; av[7] = a1.w;
    av[8] = a2.x; av[9] = a2.y; av[10] = a2.z; av[11] = a2.w;
    av[12] = a3.x; av[13] = a3.y; av[14] = a3.z; av[15] = a3.w;
#pragma unroll
    for (int p = 0; p < 8; ++p) S[p] = av[p] * (S[p] + bf2f((ushort)m0[p]));
#pragma unroll
    for (int p = 0; p < 8; ++p) S[8 + p] = av[8 + p] * (S[8 + p] + bf2f((ushort)m1[p]));

    m0 = n0; m1 = n1; a0 = b0; a1 = b1; a2 = b2; a3 = b3;
  }
}

// ---------------- scan Y: per (bh,c): A = causal(kA.kIA^T); y = kA.S0F + A.V --
__global__ __launch_bounds__(256, 1) void scan_y3(
    const ushort* __restrict__ kb, const ushort* __restrict__ zb,
    const ushort* __restrict__ vbF, const ushort* __restrict__ rb,
    const ushort* __restrict__ S0F, const float* __restrict__ bwp,
    ushort* __restrict__ yrow) {
  __shared__ ushort kt[64 * 72];
  __shared__ ushort zt[64 * 72];
  __shared__ ushort kAf[4096];
  __shared__ ushort kIAfB[4096];
  __shared__ ushort Am[64 * 72];
  __shared__ float part[256];
  const int bh = blockIdx.x, c = blockIdx.y;
  const int b = bh / H_, h = bh % H_;
  const int tid = threadIdx.x;
  const int w = tid >> 6, lane = tid & 63;
  const int fr = lane & 15, fq = lane >> 4;
  const int row = tid >> 2, c16 = (tid & 3) * 16;
  const float bwh = bwp[h * 64];
  const int swz = fragswz(lane);

  {
    const ushort* gk = kb + ((size_t)(b * T_ + c * TC + row)) * 768 + h * 64 + c16;
    const ushort* gz = zb + ((size_t)(b * T_ + c * TC + row)) * 768 + h * 64 + c16;
    uint4 k0 = *(const uint4*)gk, k1 = *(const uint4*)(gk + 8);
    uint4 z0 = *(const uint4*)gz, z1 = *(const uint4*)(gz + 8);
    *reinterpret_cast<uint4*>(&kt[row * 72 + c16]) = k0;
    *reinterpret_cast<uint4*>(&kt[row * 72 + c16 + 8]) = k1;
    *reinterpret_cast<uint4*>(&zt[row * 72 + c16]) = z0;
    *reinterpret_cast<uint4*>(&zt[row * 72 + c16 + 8]) = z1;
  }
  bf16x8 vfr[8];
  {
    const ushort* vch = vbF + ((size_t)bh * NC + c) * 4096;
#pragma unroll
    for (int f = 0; f < 8; ++f)
      vfr[f] = *reinterpret_cast<const bf16x8*>(vch + f * 512 + lane * 8);
  }
  ushort rr[16];
  {
    const ushort* rrow = rb + ((size_t)(b * T_ + c * TC)) * 768 + h * 64;
#pragma unroll
    for (int tp = 0; tp < 4; ++tp)
#pragma unroll
      for (int nf = 0; nf < 4; ++nf)
        rr[tp * 4 + nf] = rrow[(size_t)(w * 16 + fq * 4 + tp) * 768 + nf * 16 + fr];
  }
  __syncthreads();
  float dreg[16];
  float p = 1.f;
#pragma unroll
  for (int tt = 0; tt < 16; ++tt) {
    float z = bf2f(zt[(w * 16 + tt) * 72 + lane]);
    float d = 1.f / (1.f + __expf(z + bwh));
    dreg[tt] = d;
    p *= d;
  }
  part[w * 64 + lane] = p;
  __syncthreads();
  float a = 1.f;
  for (int w2 = 0; w2 < w; ++w2) a *= part[w2 * 64 + lane];
#pragma unroll
  for (int tt = 0; tt < 16; ++tt) {
    int t = w * 16 + tt;
    float k = bf2f(kt[t * 72 + lane]);
    a *= dreg[tt];
    int ad = fragaddr(t, lane) ^ swz;
    kAf[ad] = f2bf(k * a);
    kIAfB[ad] = f2bf(k / a);
  }
  __syncthreads();

  bf16x8 af[2];
#pragma unroll
  for (int kk = 0; kk < 2; ++kk) {
    int ra = ((w * 2 + kk) * 512 + lane * 8) ^ (((lane >> 4) << 3) ^ (kk << 5));
    af[kk] = *reinterpret_cast<const bf16x8*>(&kAf[ra]);
  }
  {
    f32x4 accA[4];
#pragma unroll
    for (int nf = 0; nf < 4; ++nf) accA[nf] = (f32x4){0.f, 0.f, 0.f, 0.f};
#pragma unroll
    for (int kk = 0; kk < 2; ++kk)
#pragma unroll
      for (int nf = 0; nf < 4; ++nf) {
        int rb8 = ((nf * 2 + kk) * 512 + lane * 8) ^ (((lane >> 4) << 3) ^ (kk << 5));
        bf16x8 b8 = *reinterpret_cast<const bf16x8*>(&kIAfB[rb8]);
        accA[nf] = __builtin_amdgcn_mfma_f32_16x16x32_bf16(af[kk], b8, accA[nf], 0, 0, 0);
      }
#pragma unroll
    for (int nf = 0; nf < 4; ++nf)
#pragma unroll
      for (int q = 0; q < 4; ++q) {
        int t = w * 16 + fq * 4 + q;
        int s = nf * 16 + fr;
        Am[t * 72 + s] = f2bf((s <= t) ? accA[nf][q] : 0.f);
      }
  }
  __syncthreads();

  f32x4 accY[4];
#pragma unroll
  for (int nf = 0; nf < 4; ++nf) accY[nf] = (f32x4){0.f, 0.f, 0.f, 0.f};
  const ushort* s0ch = S0F + ((size_t)bh * NC + c) * 4096;
#pragma unroll
  for (int kk = 0; kk < 2; ++kk)
#pragma unroll
    for (int nf = 0; nf < 4; ++nf) {
      bf16x8 b8 = *reinterpret_cast<const bf16x8*>(s0ch + (nf * 2 + kk) * 512 + lane * 8);
      accY[nf] = __builtin_amdgcn_mfma_f32_16x16x32_bf16(af[kk], b8, accY[nf], 0, 0, 0);
    }
#pragma unroll
  for (int kk = 0; kk < 2; ++kk) {
    bf16x8 am8 = *reinterpret_cast<const bf16x8*>(&Am[(w * 16 + fr) * 72 + kk * 32 + fq * 8]);
#pragma unroll
    for (int nf = 0; nf < 4; ++nf)
      accY[nf] = __builtin_amdgcn_mfma_f32_16x16x32_bf16(am8, vfr[nf * 2 + kk], accY[nf], 0, 0, 0);
  }
#pragma unroll
  for (int nf = 0; nf < 4; ++nf)
#pragma unroll
    for (int q = 0; q < 4; ++q) {
      int t = w * 16 + fq * 4 + q;
      int j = nf * 16 + fr;
      size_t go = ((size_t)(b * T_ + c * TC + t)) * 768 + h * 64 + j;
      yrow[go] = f2bf(accY[nf][q] * bf2f(rr[q * 4 + nf]));
    }
}

// ---------------- launch ----------------
extern "C" void kernel_launch(void* const* d_in, const int* in_sizes, int n_in,
                              void* d_out, int out_size, void* d_ws, size_t ws_size,
                              hipStream_t stream) {
  const float* x     = (const float*)d_in[0];
  const float* Wx    = (const float*)d_in[1];
  const float* Ww    = (const float*)d_in[2];
  const float* bw    = (const float*)d_in[3];
  const float* Wk    = (const float*)d_in[4];
  const float* Wv    = (const float*)d_in[5];
  const float* Wr    = (const float*)d_in[6];
  const float* Wo    = (const float*)d_in[7];
  const float* gamma = (const float*)d_in[8];
  const float* beta  = (const float*)d_in[9];
  float* out = (float*)d_out;

  // workspace (bytes), NEED proven rounds 3-10:
  //   xn   [0,          25165824)  bf16 xn -> McT (after cat)
  //   wb   [25165824,   32243712)  6 slots: Wk,Wv,Wr,M,Wo,Ww
  //   WxT  [32243712,   57409536)  WxT (dead after M-gemm) -> S0F
  //   kb   [57409536,   82575360)
  //   vbF  [82575360,  107741184)  v fragment layout per (bh,c)
  //   rb   [107741184, 132907008)
  //   yr   [132907008, 158072832)  head = aend fp32 (dead before scan_y3 writes)
  //   zb   [158072832, 183238656)  bf16 z
  const size_t NEED = 208404480ull;
  if (ws_size < NEED) {
    zero_out_kernel<<<2048, 256, 0, stream>>>(out, out_size);
    return;
  }

  char* ws = (char*)d_ws;
  ushort* xn  = (ushort*)ws;
  ushort* wb  = (ushort*)(ws + 25165824);
  ushort* WxT = (ushort*)(ws + 32243712);
  ushort* kb  = (ushort*)(ws + 57409536);
  ushort* vbF = (ushort*)(ws + 82575360);
  ushort* rb  = (ushort*)(ws + 107741184);
  ushort* yr  = (ushort*)(ws + 132907008);
  ushort* zb  = (ushort*)(ws + 158072832);
  ushort* McT = (ushort*)ws;                 // aliases xn (dead after cat)
  ushort* S0F = (ushort*)(ws + 32243712);    // aliases WxT (dead after M-gemm)
  float*  aendb = (float*)(ws + 132907008);  // yr head (dead before scan_y3)

  ushort* WcatB = wb;                 // slots 0..3: Wk, Wv, Wr, M
  ushort* Mb  = wb + 3 * 589824;
  ushort* WoB = wb + 4 * 589824;
  ushort* WwB = wb + 5 * 589824;

  cast5_kernel<<<dim3(576, 5), 256, 0, stream>>>(Wk, Wv, Wr, Wo, Ww, wb);
  transpose_cast_kernel<<<dim3(24, 24), 256, 0, stream>>>(Wx, WxT);
  // composite M = Ww @ Wx
  gemm256<<<dim3(3, 3), 512, 0, stream>>>(WwB, WxT, nullptr, Mb, nullptr, nullptr,
                                          nullptr, 5);
  ln_kernel<<<4096, 256, 0, stream>>>(x, gamma, beta, xn);

  // fused k/v/r/z GEMM (N=3072): k bf16, v frag, r sigmoid bf16, z bf16
  gemm256<<<dim3(64, 12), 512, 0, stream>>>(xn, WcatB, nullptr, kb, vbF, rb, zb, 5);

  scan_mc3<<<dim3(96, NC), 256, 0, stream>>>(kb, zb, vbF, bw, McT, aendb);
  scan_chain3<<<96, 256, 0, stream>>>(McT, aendb, S0F);
  scan_y3<<<dim3(96, NC), 256, 0, stream>>>(kb, zb, vbF, rb, S0F, bw, yr);

  // final GEMM (N=768): fp32 out
  gemm256<<<dim3(64, 3), 512, 0, stream>>>(yr, WoB, out, nullptr, nullptr, nullptr,
                                           nullptr, 0);
}

// Round 12
// 238.708 us; speedup vs baseline: 2.2461x; 1.0126x over previous
//
#include <hip/hip_runtime.h>

#define B_ 8
#define T_ 2048
#define D_ 768
#define H_ 12
#define HS_ 64
#define LN_EPS 1e-5f
#define NC 32   // chunks
#define TC 64   // timesteps per chunk

typedef __attribute__((ext_vector_type(8))) short bf16x8;
typedef __attribute__((ext_vector_type(4))) float f32x4;

__device__ __forceinline__ ushort f2bf(float f) {
  unsigned u = __builtin_bit_cast(unsigned, f);
  unsigned r = (u + 0x7FFFu + ((u >> 16) & 1u)) >> 16;
  return (ushort)r;
}
__device__ __forceinline__ float bf2f(ushort u) {
  return __builtin_bit_cast(float, ((unsigned)u) << 16);
}

// fragment address: element (row t, col i) of a 64x64 tile in MFMA A/B-frag
// layout (m/n = t, k = i). 8 frags x 512 halves.
__device__ __forceinline__ int fragaddr(int t, int i) {
  return ((t >> 4) * 2 + (i >> 5)) * 512 + ((((i >> 3) & 3) * 16) + (t & 15)) * 8 + (i & 7);
}
__device__ __forceinline__ int fragswz(int i) {
  return (((i >> 3) & 3) << 3) ^ (((i >> 5) & 1) << 5);
}

// ---------------- canary ----------------
__global__ __launch_bounds__(256) void zero_out_kernel(float* __restrict__ out, int n) {
  for (int i = blockIdx.x * 256 + threadIdx.x; i < n; i += gridDim.x * 256)
    out[i] = 0.f;
}

// ---------------- prep: 5 casts (slots 0,1,2,4,5) + WxT transpose ----------------
__global__ __launch_bounds__(256) void prep_kernel(
    const float* __restrict__ w0, const float* __restrict__ w1,
    const float* __restrict__ w2, const float* __restrict__ w3,
    const float* __restrict__ w4, const float* __restrict__ Wx,
    ushort* __restrict__ dst, ushort* __restrict__ WxT) {
  if (blockIdx.y < 5) {
    const float* srcs[5] = {w0, w1, w2, w3, w4};
    const int slots[5] = {0, 1, 2, 4, 5};
    const float* src = srcs[blockIdx.y];
    ushort* d = dst + (size_t)slots[blockIdx.y] * 589824;
    int idx = (blockIdx.x * 256 + threadIdx.x) * 4;
    float4 v = *reinterpret_cast<const float4*>(src + idx);
    ushort4 o;
    o.x = f2bf(v.x); o.y = f2bf(v.y); o.z = f2bf(v.z); o.w = f2bf(v.w);
    *reinterpret_cast<ushort4*>(d + idx) = o;
  } else {
    __shared__ ushort tile[32][33];
    const int bx = (blockIdx.x % 24) * 32;
    const int by = (blockIdx.x / 24) * 32;
    const int tx = threadIdx.x & 31, ty = threadIdx.x >> 5;
#pragma unroll
    for (int r = 0; r < 32; r += 8)
      tile[ty + r][tx] = f2bf(Wx[(size_t)(by + ty + r) * 768 + bx + tx]);
    __syncthreads();
#pragma unroll
    for (int r = 0; r < 32; r += 8)
      WxT[(size_t)(bx + ty + r) * 768 + by + tx] = tile[tx][ty + r];
  }
}

// ---------------- LayerNorm ----------------
__global__ __launch_bounds__(256) void ln_kernel(
    const float* __restrict__ x, const float* __restrict__ gamma,
    const float* __restrict__ beta, ushort* __restrict__ xn) {
  const int wv = threadIdx.x >> 6;
  const int lane = threadIdx.x & 63;
  const int row = blockIdx.x * 4 + wv;
  const float* xr = x + (size_t)row * D_;
  float4 a[3];
#pragma unroll
  for (int s = 0; s < 3; ++s)
    a[s] = *reinterpret_cast<const float4*>(xr + s * 256 + lane * 4);
  float sum = 0.f;
#pragma unroll
  for (int s = 0; s < 3; ++s) sum += a[s].x + a[s].y + a[s].z + a[s].w;
#pragma unroll
  for (int off = 32; off; off >>= 1) sum += __shfl_xor(sum, off);
  float mu = sum * (1.f / 768.f);
  float vs = 0.f;
#pragma unroll
  for (int s = 0; s < 3; ++s) {
    float dx = a[s].x - mu, dy = a[s].y - mu, dz = a[s].z - mu, dw = a[s].w - mu;
    vs += dx * dx + dy * dy + dz * dz + dw * dw;
  }
#pragma unroll
  for (int off = 32; off; off >>= 1) vs += __shfl_xor(vs, off);
  float rs = rsqrtf(vs * (1.f / 768.f) + LN_EPS);
  ushort* orow = xn + (size_t)row * D_;
#pragma unroll
  for (int s = 0; s < 3; ++s) {
    int col = s * 256 + lane * 4;
    float4 g = *reinterpret_cast<const float4*>(gamma + col);
    float4 bb = *reinterpret_cast<const float4*>(beta + col);
    ushort4 o;
    o.x = f2bf((a[s].x - mu) * rs * g.x + bb.x);
    o.y = f2bf((a[s].y - mu) * rs * g.y + bb.y);
    o.z = f2bf((a[s].z - mu) * rs * g.z + bb.z);
    o.w = f2bf((a[s].w - mu) * rs * g.w + bb.w);
    *reinterpret_cast<ushort4*>(orow + col) = o;
  }
}

// ---------------- 256x256 superphase bf16 MFMA GEMM ----------------
// C[m,n] = sum_k A[m,k]*W[n,k].  K=768. 512 threads = 8 waves (2M x 4N).
// Two superphases per K-tile: {stage A(next); read aL,bL,bH; bar; 32 MFMA; bar}
// {stage B(+2); read aH; bar; 32 MFMA; vmcnt(4); bar}. Barriers/K-tile: 8 -> 4.
// modes: 0 fp32 plain
//        5 cat -> sel0: d0 bf16 | sel1: d1 v FRAG layout | sel2: d2 sigmoid bf16
//                 sel3: d3 bf16 plain (z)
__global__ __launch_bounds__(512, 2) void gemm256(
    const ushort* __restrict__ A, const ushort* __restrict__ W,
    float* __restrict__ Cf,
    ushort* __restrict__ d0, ushort* __restrict__ d1,
    ushort* __restrict__ d2, ushort* __restrict__ d3, int mode) {
  __shared__ __align__(16) ushort lds[65536];  // 128 KiB
  const int tid = threadIdx.x;
  const int wid = tid >> 6;
  const int lane = tid & 63;
  const int wr = wid >> 2, wc = wid & 3;
  const int fr = lane & 15, fq = lane >> 4;
  const int m0 = blockIdx.x * 256, n0 = blockIdx.y * 256;
  const int strow = tid >> 3;
  const int stblk = tid & 7;

  const int RA0 = wr * 8192;
  const int RA1 = 32768 + wr * 8192;
  const int RB0 = 16384 + (wc >> 1) * 8192 + (wc & 1) * 4096;
  const int RB1 = 49152 + (wc >> 1) * 8192 + (wc & 1) * 4096;

  f32x4 acc[8][4];
#pragma unroll
  for (int m = 0; m < 8; ++m)
#pragma unroll
    for (int n = 0; n < 4; ++n) acc[m][n] = (f32x4){0.f, 0.f, 0.f, 0.f};

#define STAGE_HALF(gb, grow0, kk0, roff)                                          \
  {                                                                               \
    _Pragma("unroll") for (int j = 0; j < 2; ++j) {                               \
      const int lr_ = j * 64 + strow;                                             \
      const int bs_ = stblk ^ (lr_ & 7);                                          \
      const ushort* s_ = (gb) + (size_t)((grow0) + lr_) * 768 + (kk0) + bs_ * 8;  \
      __builtin_amdgcn_global_load_lds(                                           \
          (const __attribute__((address_space(1))) void*)s_,                      \
          (__attribute__((address_space(3))) void*)(lds + (roff) + j * 4096 + wid * 512), \
          16, 0, 0);                                                              \
    }                                                                             \
  }

#define LDF(dst, base, rf, kk)                                                    \
  dst = *reinterpret_cast<const bf16x8*>(                                         \
      lds + (base) + ((rf)*16 + fr) * 64 + ((((kk)*4 + fq) ^ (fr & 7)) * 8));

#define MFMA_Q(mb, nb, aa, bb)                                                    \
  _Pragma("unroll") for (int m_ = 0; m_ < 4; ++m_)                                \
  _Pragma("unroll") for (int n_ = 0; n_ < 2; ++n_)                                \
  _Pragma("unroll") for (int k_ = 0; k_ < 2; ++k_)                                \
    acc[(mb) + m_][(nb) + n_] = __builtin_amdgcn_mfma_f32_16x16x32_bf16(          \
        aa[m_][k_], bb[n_][k_], acc[(mb) + m_][(nb) + n_], 0, 0, 0);

#define LDF_AL(RA) \
  _Pragma("unroll") for (int m = 0; m < 4; ++m) { LDF(aL[m][0], RA, m, 0); LDF(aL[m][1], RA, m, 1); }
#define LDF_AH(RA) \
  _Pragma("unroll") for (int m = 0; m < 4; ++m) { LDF(aH[m][0], RA, m + 4, 0); LDF(aH[m][1], RA, m + 4, 1); }
#define LDF_BL(RB) \
  _Pragma("unroll") for (int n = 0; n < 2; ++n) { LDF(bL[n][0], RB, n, 0); LDF(bL[n][1], RB, n, 1); }
#define LDF_BH(RB) \
  _Pragma("unroll") for (int n = 0; n < 2; ++n) { LDF(bH[n][0], RB, n + 2, 0); LDF(bH[n][1], RB, n + 2, 1); }

  // ---- prologue: A0, B0 -> buf0; B1 -> buf1 ----
  STAGE_HALF(A, m0, 0, 0);
  STAGE_HALF(A, m0 + 128, 0, 8192);
  STAGE_HALF(W, n0, 0, 16384);
  STAGE_HALF(W, n0 + 128, 0, 24576);
  STAGE_HALF(W, n0, 64, 49152);
  STAGE_HALF(W, n0 + 128, 64, 57344);
  asm volatile("s_waitcnt vmcnt(4)" ::: "memory");
  __builtin_amdgcn_s_barrier();

  bf16x8 aL[4][2], aH[4][2], bL[2][2], bH[2][2];

  for (int i = 0; i < 6; ++i) {
    const int kQ = (2 * i + 1) * 64;
    const int kP2 = (2 * i + 2 <= 11 ? 2 * i + 2 : 11) * 64;
    const int kQ2 = (2 * i + 3 <= 11 ? 2 * i + 3 : 11) * 64;

    // ======== tile P = 2i (buf0) ========
    // sp1: stage A(Q) -> Abuf1; read aL,bL,bH; 32 MFMA
    STAGE_HALF(A, m0, kQ, 32768);
    STAGE_HALF(A, m0 + 128, kQ, 40960);
    LDF_AL(RA0);
    LDF_BL(RB0);
    LDF_BH(RB0);
    __builtin_amdgcn_s_barrier();
    __builtin_amdgcn_s_setprio(1);
    MFMA_Q(0, 0, aL, bL);
    MFMA_Q(0, 2, aL, bH);
    __builtin_amdgcn_s_setprio(0);
    __builtin_amdgcn_s_barrier();
    // sp2: stage B(P+2) -> Bbuf0; read aH; 32 MFMA; vmcnt(4)
    STAGE_HALF(W, n0, kP2, 16384);
    STAGE_HALF(W, n0 + 128, kP2, 24576);
    LDF_AH(RA0);
    __builtin_amdgcn_s_barrier();
    __builtin_amdgcn_s_setprio(1);
    MFMA_Q(4, 0, aH, bL);
    MFMA_Q(4, 2, aH, bH);
    __builtin_amdgcn_s_setprio(0);
    asm volatile("s_waitcnt vmcnt(4)" ::: "memory");
    __builtin_amdgcn_s_barrier();

    // ======== tile Q = 2i+1 (buf1) ========
    STAGE_HALF(A, m0, kP2, 0);
    STAGE_HALF(A, m0 + 128, kP2, 8192);
    LDF_AL(RA1);
    LDF_BL(RB1);
    LDF_BH(RB1);
    __builtin_amdgcn_s_barrier();
    __builtin_amdgcn_s_setprio(1);
    MFMA_Q(0, 0, aL, bL);
    MFMA_Q(0, 2, aL, bH);
    __builtin_amdgcn_s_setprio(0);
    __builtin_amdgcn_s_barrier();
    STAGE_HALF(W, n0, kQ2, 49152);
    STAGE_HALF(W, n0 + 128, kQ2, 57344);
    LDF_AH(RA1);
    __builtin_amdgcn_s_barrier();
    __builtin_amdgcn_s_setprio(1);
    MFMA_Q(4, 0, aH, bL);
    MFMA_Q(4, 2, aH, bH);
    __builtin_amdgcn_s_setprio(0);
    asm volatile("s_waitcnt vmcnt(4)" ::: "memory");
    __builtin_amdgcn_s_barrier();
  }

  // ---- epilogue ----
  const int r0 = fq * 4;
  if (mode == 5) {
    const int sel = n0 >= 2304 ? 3 : n0 >= 1536 ? 2 : n0 >= 768 ? 1 : 0;
    const int nb = n0 - sel * 768;
    if (sel == 1) {
#pragma unroll
      for (int mf = 0; mf < 8; ++mf)
#pragma unroll
        for (int nf = 0; nf < 4; ++nf) {
          int gr = m0 + wr * 128 + mf * 16 + r0;
          int gc = nb + wc * 64 + nf * 16 + fr;
          int b = gr >> 11, t = gr & 2047;
          int c = t >> 6, s0 = t & 63;
          int h = gc >> 6, j = gc & 63;
          size_t addr = ((size_t)((b * 12 + h) * 32 + c)) * 4096 +
                        (size_t)(((j >> 4) * 2 + (s0 >> 5)) * 512 +
                                 (((s0 >> 3) & 3) * 16 + (j & 15)) * 8 + (s0 & 7));
          ushort4 o;
          o.x = f2bf(acc[mf][nf][0]); o.y = f2bf(acc[mf][nf][1]);
          o.z = f2bf(acc[mf][nf][2]); o.w = f2bf(acc[mf][nf][3]);
          *reinterpret_cast<ushort4*>(d1 + addr) = o;
        }
    } else {
      ushort* dst = sel == 0 ? d0 : sel == 2 ? d2 : d3;
      const bool sig = (sel == 2);
#pragma unroll
      for (int mf = 0; mf < 8; ++mf)
#pragma unroll
        for (int nf = 0; nf < 4; ++nf) {
          int gr = m0 + wr * 128 + mf * 16 + r0;
          int gc = nb + wc * 64 + nf * 16 + fr;
#pragma unroll
          for (int rr = 0; rr < 4; ++rr) {
            float v = acc[mf][nf][rr];
            if (sig) v = 1.f / (1.f + __expf(-v));
            dst[(size_t)(gr + rr) * 768 + gc] = f2bf(v);
          }
        }
    }
  } else {
#pragma unroll
    for (int mf = 0; mf < 8; ++mf)
#pragma unroll
      for (int nf = 0; nf < 4; ++nf) {
        int gr = m0 + wr * 128 + mf * 16 + r0;
        int gc = n0 + wc * 64 + nf * 16 + fr;
#pragma unroll
        for (int rr = 0; rr < 4; ++rr)
          Cf[(size_t)(gr + rr) * 768 + gc] = acc[mf][nf][rr];
      }
  }
#undef STAGE_HALF
#undef LDF
#undef MFMA_Q
#undef LDF_AL
#undef LDF_AH
#undef LDF_BL
#undef LDF_BH
}

// ---------------- scan P: per (bh,c): cumprod + Mc = kIA^T V (parallel) ------
__global__ __launch_bounds__(256) void scan_mc3(
    const ushort* __restrict__ kb, const ushort* __restrict__ zb,
    const ushort* __restrict__ vbF, const float* __restrict__ bwp,
    ushort* __restrict__ McT, float* __restrict__ aend) {
  __shared__ ushort kt[64 * 72];
  __shared__ ushort zt[64 * 72];
  __shared__ ushort kIAfA[4096];
  __shared__ float part[256];
  const int bh = blockIdx.x, c = blockIdx.y;
  const int b = bh / H_, h = bh % H_;
  const int tid = threadIdx.x;
  const int w = tid >> 6, lane = tid & 63;
  const int fr = lane & 15, fq = lane >> 4;
  const int row = tid >> 2, c16 = (tid & 3) * 16;
  const float bwh = bwp[h * 64];

  {
    const ushort* gk = kb + ((size_t)(b * T_ + c * TC + row)) * 768 + h * 64 + c16;
    const ushort* gz = zb + ((size_t)(b * T_ + c * TC + row)) * 768 + h * 64 + c16;
    uint4 k0 = *(const uint4*)gk, k1 = *(const uint4*)(gk + 8);
    uint4 z0 = *(const uint4*)gz, z1 = *(const uint4*)(gz + 8);
    *reinterpret_cast<uint4*>(&kt[row * 72 + c16]) = k0;
    *reinterpret_cast<uint4*>(&kt[row * 72 + c16 + 8]) = k1;
    *reinterpret_cast<uint4*>(&zt[row * 72 + c16]) = z0;
    *reinterpret_cast<uint4*>(&zt[row * 72 + c16 + 8]) = z1;
  }
  bf16x8 vfr[8];
  {
    const ushort* vch = vbF + ((size_t)bh * NC + c) * 4096;
#pragma unroll
    for (int f = 0; f < 8; ++f)
      vfr[f] = *reinterpret_cast<const bf16x8*>(vch + f * 512 + lane * 8);
  }
  __syncthreads();
  float dreg[16];
  float p = 1.f;
#pragma unroll
  for (int tt = 0; tt < 16; ++tt) {
    float z = bf2f(zt[(w * 16 + tt) * 72 + lane]);
    float d = 1.f / (1.f + __expf(z + bwh));
    dreg[tt] = d;
    p *= d;
  }
  part[w * 64 + lane] = p;
  __syncthreads();
  float a = 1.f;
  for (int w2 = 0; w2 < w; ++w2) a *= part[w2 * 64 + lane];
  if (w == 0)
    aend[((size_t)bh * NC + c) * 64 + lane] =
        part[lane] * part[64 + lane] * part[128 + lane] * part[192 + lane];
#pragma unroll
  for (int tt = 0; tt < 16; ++tt) {
    int t = w * 16 + tt;
    float k = bf2f(kt[t * 72 + lane]);
    a *= dreg[tt];
    kIAfA[fragaddr(lane, t)] = f2bf(k / a);  // A-frag (m=i, k=s)
  }
  __syncthreads();

  bf16x8 af2[2];
#pragma unroll
  for (int kk = 0; kk < 2; ++kk)
    af2[kk] = *reinterpret_cast<const bf16x8*>(&kIAfA[(w * 2 + kk) * 512 + lane * 8]);
  f32x4 accM[4];
#pragma unroll
  for (int nf = 0; nf < 4; ++nf) accM[nf] = (f32x4){0.f, 0.f, 0.f, 0.f};
#pragma unroll
  for (int kk = 0; kk < 2; ++kk)
#pragma unroll
    for (int nf = 0; nf < 4; ++nf)
      accM[nf] = __builtin_amdgcn_mfma_f32_16x16x32_bf16(af2[kk], vfr[nf * 2 + kk], accM[nf], 0, 0, 0);
  ushort* mch = McT + ((size_t)bh * NC + c) * 4096;
#pragma unroll
  for (int nf = 0; nf < 4; ++nf) {
    ushort4 o;
    o.x = f2bf(accM[nf][0]); o.y = f2bf(accM[nf][1]);
    o.z = f2bf(accM[nf][2]); o.w = f2bf(accM[nf][3]);
    *reinterpret_cast<ushort4*>(&mch[(nf * 16 + fr) * 64 + w * 16 + fq * 4]) = o;
  }
}

// ---------------- scan C: chain with register prefetch (96 blocks) -----------
__global__ __launch_bounds__(256) void scan_chain3(
    const ushort* __restrict__ McT, const float* __restrict__ aend,
    ushort* __restrict__ S0F) {
  const int bh = blockIdx.x;
  const int j = threadIdx.x >> 2, i0 = (threadIdx.x & 3) * 16;
  const int fbase = ((j >> 4) * 2 + (i0 >> 5)) * 512 + (((i0 >> 3) & 3) * 16 + (j & 15)) * 8;
  float S[16];
#pragma unroll
  for (int p = 0; p < 16; ++p) S[p] = 0.f;

  const ushort* mch0 = McT + ((size_t)bh * NC) * 4096 + j * 64 + i0;
  const float* aep0 = aend + ((size_t)bh * NC) * 64 + i0;
  bf16x8 m0 = *reinterpret_cast<const bf16x8*>(mch0);
  bf16x8 m1 = *reinterpret_cast<const bf16x8*>(mch0 + 8);
  float4 a0 = *(const float4*)(aep0);
  float4 a1 = *(const float4*)(aep0 + 4);
  float4 a2 = *(const float4*)(aep0 + 8);
  float4 a3 = *(const float4*)(aep0 + 12);

  for (int c = 0; c < NC; ++c) {
    int cn = c + 1 < NC ? c + 1 : NC - 1;
    const ushort* mchn = McT + ((size_t)bh * NC + cn) * 4096 + j * 64 + i0;
    const float* aepn = aend + ((size_t)bh * NC + cn) * 64 + i0;
    bf16x8 n0 = *reinterpret_cast<const bf16x8*>(mchn);
    bf16x8 n1 = *reinterpret_cast<const bf16x8*>(mchn + 8);
    float4 b0 = *(const float4*)(aepn);
    float4 b1 = *(const float4*)(aepn + 4);
    float4 b2 = *(const float4*)(aepn + 8);
    float4 b3 = *(const float4*)(aepn + 12);

    ushort* s0 = S0F + ((size_t)bh * NC + c) * 4096 + fbase;
    ushort4 o0, o1, o2, o3;
    o0.x = f2bf(S[0]); o0.y = f2bf(S[1]); o0.z = f2bf(S[2]); o0.w = f2bf(S[3]);
    o1.x = f2bf(S[4]); o1.y = f2bf(S[5]); o1.z = f2bf(S[6]); o1.w = f2bf(S[7]);
    o2.x = f2bf(S[8]); o2.y = f2bf(S[9]); o2.z = f2bf(S[10]); o2.w = f2bf(S[11]);
    o3.x = f2bf(S[12]); o3.y = f2bf(S[13]); o3.z = f2bf(S[14]); o3.w = f2bf(S[15]);
    *reinterpret_cast<ushort4*>(s0) = o0;
    *reinterpret_cast<ushort4*>(s0 + 4) = o1;
    *reinterpret_cast<ushort4*>(s0 + 128) = o2;
    *reinterpret_cast<ushort4*>(s0 + 132) = o3;

    float av[16];
    av[0] = a0.x; av[1] = a0.y; av[2] = a0.z; av[3] = a0.w;
    av[4] = a1.x; av[5] = a1.y; av[6] = a1.z; av[7] = a1.w;
    av[8] = a2.x; av[9] = a2.y; av[10] = a2.z; av[11] = a2.w;
    av[12] = a3.x; av[13] = a3.y; av[14] = a3.z; av[15] = a3.w;
#pragma unroll
    for (int p = 0; p < 8; ++p) S[p] = av[p] * (S[p] + bf2f((ushort)m0[p]));
#pragma unroll
    for (int p = 0; p < 8; ++p) S[8 + p] = av[8 + p] * (S[8 + p] + bf2f((ushort)m1[p]));

    m0 = n0; m1 = n1; a0 = b0; a1 = b1; a2 = b2; a3 = b3;
  }
}

// ---------------- scan Y: per (bh,c): A = causal(kA.kIA^T); y = kA.S0F + A.V --
__global__ __launch_bounds__(256, 1) void scan_y3(
    const ushort* __restrict__ kb, const ushort* __restrict__ zb,
    const ushort* __restrict__ vbF, const ushort* __restrict__ rb,
    const ushort* __restrict__ S0F, const float* __restrict__ bwp,
    ushort* __restrict__ yrow) {
  __shared__ ushort kt[64 * 72];
  __shared__ ushort zt[64 * 72];
  __shared__ ushort kAf[4096];
  __shared__ ushort kIAfB[4096];
  __shared__ ushort Am[64 * 72];
  __shared__ float part[256];
  const int bh = blockIdx.x, c = blockIdx.y;
  const int b = bh / H_, h = bh % H_;
  const int tid = threadIdx.x;
  const int w = tid >> 6, lane = tid & 63;
  const int fr = lane & 15, fq = lane >> 4;
  const int row = tid >> 2, c16 = (tid & 3) * 16;
  const float bwh = bwp[h * 64];
  const int swz = fragswz(lane);

  {
    const ushort* gk = kb + ((size_t)(b * T_ + c * TC + row)) * 768 + h * 64 + c16;
    const ushort* gz = zb + ((size_t)(b * T_ + c * TC + row)) * 768 + h * 64 + c16;
    uint4 k0 = *(const uint4*)gk, k1 = *(const uint4*)(gk + 8);
    uint4 z0 = *(const uint4*)gz, z1 = *(const uint4*)(gz + 8);
    *reinterpret_cast<uint4*>(&kt[row * 72 + c16]) = k0;
    *reinterpret_cast<uint4*>(&kt[row * 72 + c16 + 8]) = k1;
    *reinterpret_cast<uint4*>(&zt[row * 72 + c16]) = z0;
    *reinterpret_cast<uint4*>(&zt[row * 72 + c16 + 8]) = z1;
  }
  bf16x8 vfr[8];
  {
    const ushort* vch = vbF + ((size_t)bh * NC + c) * 4096;
#pragma unroll
    for (int f = 0; f < 8; ++f)
      vfr[f] = *reinterpret_cast<const bf16x8*>(vch + f * 512 + lane * 8);
  }
  ushort rr[16];
  {
    const ushort* rrow = rb + ((size_t)(b * T_ + c * TC)) * 768 + h * 64;
#pragma unroll
    for (int tp = 0; tp < 4; ++tp)
#pragma unroll
      for (int nf = 0; nf < 4; ++nf)
        rr[tp * 4 + nf] = rrow[(size_t)(w * 16 + fq * 4 + tp) * 768 + nf * 16 + fr];
  }
  __syncthreads();
  float dreg[16];
  float p = 1.f;
#pragma unroll
  for (int tt = 0; tt < 16; ++tt) {
    float z = bf2f(zt[(w * 16 + tt) * 72 + lane]);
    float d = 1.f / (1.f + __expf(z + bwh));
    dreg[tt] = d;
    p *= d;
  }
  part[w * 64 + lane] = p;
  __syncthreads();
  float a = 1.f;
  for (int w2 = 0; w2 < w; ++w2) a *= part[w2 * 64 + lane];
#pragma unroll
  for (int tt = 0; tt < 16; ++tt) {
    int t = w * 16 + tt;
    float k = bf2f(kt[t * 72 + lane]);
    a *= dreg[tt];
    int ad = fragaddr(t, lane) ^ swz;
    kAf[ad] = f2bf(k * a);
    kIAfB[ad] = f2bf(k / a);
  }
  __syncthreads();

  bf16x8 af[2];
#pragma unroll
  for (int kk = 0; kk < 2; ++kk) {
    int ra = ((w * 2 + kk) * 512 + lane * 8) ^ (((lane >> 4) << 3) ^ (kk << 5));
    af[kk] = *reinterpret_cast<const bf16x8*>(&kAf[ra]);
  }
  {
    f32x4 accA[4];
#pragma unroll
    for (int nf = 0; nf < 4; ++nf) accA[nf] = (f32x4){0.f, 0.f, 0.f, 0.f};
#pragma unroll
    for (int kk = 0; kk < 2; ++kk)
#pragma unroll
      for (int nf = 0; nf < 4; ++nf) {
        int rb8 = ((nf * 2 + kk) * 512 + lane * 8) ^ (((lane >> 4) << 3) ^ (kk << 5));
        bf16x8 b8 = *reinterpret_cast<const bf16x8*>(&kIAfB[rb8]);
        accA[nf] = __builtin_amdgcn_mfma_f32_16x16x32_bf16(af[kk], b8, accA[nf], 0, 0, 0);
      }
#pragma unroll
    for (int nf = 0; nf < 4; ++nf)
#pragma unroll
      for (int q = 0; q < 4; ++q) {
        int t = w * 16 + fq * 4 + q;
        int s = nf * 16 + fr;
        Am[t * 72 + s] = f2bf((s <= t) ? accA[nf][q] : 0.f);
      }
  }
  __syncthreads();

  f32x4 accY[4];
#pragma unroll
  for (int nf = 0; nf < 4; ++nf) accY[nf] = (f32x4){0.f, 0.f, 0.f, 0.f};
  const ushort* s0ch = S0F + ((size_t)bh * NC + c) * 4096;
#pragma unroll
  for (int kk = 0; kk < 2; ++kk)
#pragma unroll
    for (int nf = 0; nf < 4; ++nf) {
      bf16x8 b8 = *reinterpret_cast<const bf16x8*>(s0ch + (nf * 2 + kk) * 512 + lane * 8);
      accY[nf] = __builtin_amdgcn_mfma_f32_16x16x32_bf16(af[kk], b8, accY[nf], 0, 0, 0);
    }
#pragma unroll
  for (int kk = 0; kk < 2; ++kk) {
    bf16x8 am8 = *reinterpret_cast<const bf16x8*>(&Am[(w * 16 + fr) * 72 + kk * 32 + fq * 8]);
#pragma unroll
    for (int nf = 0; nf < 4; ++nf)
      accY[nf] = __builtin_amdgcn_mfma_f32_16x16x32_bf16(am8, vfr[nf * 2 + kk], accY[nf], 0, 0, 0);
  }
#pragma unroll
  for (int nf = 0; nf < 4; ++nf)
#pragma unroll
    for (int q = 0; q < 4; ++q) {
      int t = w * 16 + fq * 4 + q;
      int j = nf * 16 + fr;
      size_t go = ((size_t)(b * T_ + c * TC + t)) * 768 + h * 64 + j;
      yrow[go] = f2bf(accY[nf][q] * bf2f(rr[q * 4 + nf]));
    }
}

// ---------------- launch ----------------
extern "C" void kernel_launch(void* const* d_in, const int* in_sizes, int n_in,
                              void* d_out, int out_size, void* d_ws, size_t ws_size,
                              hipStream_t stream) {
  const float* x     = (const float*)d_in[0];
  const float* Wx    = (const float*)d_in[1];
  const float* Ww    = (const float*)d_in[2];
  const float* bw    = (const float*)d_in[3];
  const float* Wk    = (const float*)d_in[4];
  const float* Wv    = (const float*)d_in[5];
  const float* Wr    = (const float*)d_in[6];
  const float* Wo    = (const float*)d_in[7];
  const float* gamma = (const float*)d_in[8];
  const float* beta  = (const float*)d_in[9];
  float* out = (float*)d_out;

  // workspace (bytes), NEED proven rounds 3-11:
  //   xn   [0,          25165824)  bf16 xn -> McT (after cat)
  //   wb   [25165824,   32243712)  6 slots: Wk,Wv,Wr,M,Wo,Ww
  //   WxT  [32243712,   57409536)  WxT (dead after M-gemm) -> S0F
  //   kb   [57409536,   82575360)
  //   vbF  [82575360,  107741184)  v fragment layout per (bh,c)
  //   rb   [107741184, 132907008)
  //   yr   [132907008, 158072832)  head = aend fp32 (dead before scan_y3 writes)
  //   zb   [158072832, 183238656)  bf16 z
  const size_t NEED = 208404480ull;
  if (ws_size < NEED) {
    zero_out_kernel<<<2048, 256, 0, stream>>>(out, out_size);
    return;
  }

  char* ws = (char*)d_ws;
  ushort* xn  = (ushort*)ws;
  ushort* wb  = (ushort*)(ws + 25165824);
  ushort* WxT = (ushort*)(ws + 32243712);
  ushort* kb  = (ushort*)(ws + 57409536);
  ushort* vbF = (ushort*)(ws + 82575360);
  ushort* rb  = (ushort*)(ws + 107741184);
  ushort* yr  = (ushort*)(ws + 132907008);
  ushort* zb  = (ushort*)(ws + 158072832);
  ushort* McT = (ushort*)ws;                 // aliases xn (dead after cat)
  ushort* S0F = (ushort*)(ws + 32243712);    // aliases WxT (dead after M-gemm)
  float*  aendb = (float*)(ws + 132907008);  // yr head (dead before scan_y3)

  ushort* WcatB = wb;                 // slots 0..3: Wk, Wv, Wr, M
  ushort* Mb  = wb + 3 * 589824;
  ushort* WoB = wb + 4 * 589824;
  ushort* WwB = wb + 5 * 589824;

  prep_kernel<<<dim3(576, 6), 256, 0, stream>>>(Wk, Wv, Wr, Wo, Ww, Wx, wb, WxT);
  // composite M = Ww @ Wx
  gemm256<<<dim3(3, 3), 512, 0, stream>>>(WwB, WxT, nullptr, Mb, nullptr, nullptr,
                                          nullptr, 5);
  ln_kernel<<<4096, 256, 0, stream>>>(x, gamma, beta, xn);

  // fused k/v/r/z GEMM (N=3072): k bf16, v frag, r sigmoid bf16, z bf16
  gemm256<<<dim3(64, 12), 512, 0, stream>>>(xn, WcatB, nullptr, kb, vbF, rb, zb, 5);

  scan_mc3<<<dim3(96, NC), 256, 0, stream>>>(kb, zb, vbF, bw, McT, aendb);
  scan_chain3<<<96, 256, 0, stream>>>(McT, aendb, S0F);
  scan_y3<<<dim3(96, NC), 256, 0, stream>>>(kb, zb, vbF, rb, S0F, bw, yr);

  // final GEMM (N=768): fp32 out
  gemm256<<<dim3(64, 3), 512, 0, stream>>>(yr, WoB, out, nullptr, nullptr, nullptr,
                                           nullptr, 0);
}

// Round 13
// 227.712 us; speedup vs baseline: 2.3546x; 1.0483x over previous
//
#include <hip/hip_runtime.h>

#define B_ 8
#define T_ 2048
#define D_ 768
#define H_ 12
#define HS_ 64
#define LN_EPS 1e-5f
#define NC 32   // chunks
#define TC 64   // timesteps per chunk

typedef __attribute__((ext_vector_type(8))) short bf16x8;
typedef __attribute__((ext_vector_type(4))) float f32x4;

__device__ __forceinline__ ushort f2bf(float f) {
  unsigned u = __builtin_bit_cast(unsigned, f);
  unsigned r = (u + 0x7FFFu + ((u >> 16) & 1u)) >> 16;
  return (ushort)r;
}
__device__ __forceinline__ float bf2f(ushort u) {
  return __builtin_bit_cast(float, ((unsigned)u) << 16);
}

// fragment address: element (row t, col i) of a 64x64 tile in MFMA A/B-frag
// layout (m/n = t, k = i). 8 frags x 512 halves.
__device__ __forceinline__ int fragaddr(int t, int i) {
  return ((t >> 4) * 2 + (i >> 5)) * 512 + ((((i >> 3) & 3) * 16) + (t & 15)) * 8 + (i & 7);
}
__device__ __forceinline__ int fragswz(int i) {
  return (((i >> 3) & 3) << 3) ^ (((i >> 5) & 1) << 5);
}

// ---------------- canary ----------------
__global__ __launch_bounds__(256) void zero_out_kernel(float* __restrict__ out, int n) {
  for (int i = blockIdx.x * 256 + threadIdx.x; i < n; i += gridDim.x * 256)
    out[i] = 0.f;
}

// ---------------- prep: 5 casts (slots 0,1,2,4,5) + WxT transpose ----------------
__global__ __launch_bounds__(256) void prep_kernel(
    const float* __restrict__ w0, const float* __restrict__ w1,
    const float* __restrict__ w2, const float* __restrict__ w3,
    const float* __restrict__ w4, const float* __restrict__ Wx,
    ushort* __restrict__ dst, ushort* __restrict__ WxT) {
  if (blockIdx.y < 5) {
    const float* srcs[5] = {w0, w1, w2, w3, w4};
    const int slots[5] = {0, 1, 2, 4, 5};
    const float* src = srcs[blockIdx.y];
    ushort* d = dst + (size_t)slots[blockIdx.y] * 589824;
    int idx = (blockIdx.x * 256 + threadIdx.x) * 4;
    float4 v = *reinterpret_cast<const float4*>(src + idx);
    ushort4 o;
    o.x = f2bf(v.x); o.y = f2bf(v.y); o.z = f2bf(v.z); o.w = f2bf(v.w);
    *reinterpret_cast<ushort4*>(d + idx) = o;
  } else {
    __shared__ ushort tile[32][33];
    const int bx = (blockIdx.x % 24) * 32;
    const int by = (blockIdx.x / 24) * 32;
    const int tx = threadIdx.x & 31, ty = threadIdx.x >> 5;
#pragma unroll
    for (int r = 0; r < 32; r += 8)
      tile[ty + r][tx] = f2bf(Wx[(size_t)(by + ty + r) * 768 + bx + tx]);
    __syncthreads();
#pragma unroll
    for (int r = 0; r < 32; r += 8)
      WxT[(size_t)(bx + ty + r) * 768 + by + tx] = tile[tx][ty + r];
  }
}

// ---------------- LayerNorm ----------------
__global__ __launch_bounds__(256) void ln_kernel(
    const float* __restrict__ x, const float* __restrict__ gamma,
    const float* __restrict__ beta, ushort* __restrict__ xn) {
  const int wv = threadIdx.x >> 6;
  const int lane = threadIdx.x & 63;
  const int row = blockIdx.x * 4 + wv;
  const float* xr = x + (size_t)row * D_;
  float4 a[3];
#pragma unroll
  for (int s = 0; s < 3; ++s)
    a[s] = *reinterpret_cast<const float4*>(xr + s * 256 + lane * 4);
  float sum = 0.f;
#pragma unroll
  for (int s = 0; s < 3; ++s) sum += a[s].x + a[s].y + a[s].z + a[s].w;
#pragma unroll
  for (int off = 32; off; off >>= 1) sum += __shfl_xor(sum, off);
  float mu = sum * (1.f / 768.f);
  float vs = 0.f;
#pragma unroll
  for (int s = 0; s < 3; ++s) {
    float dx = a[s].x - mu, dy = a[s].y - mu, dz = a[s].z - mu, dw = a[s].w - mu;
    vs += dx * dx + dy * dy + dz * dz + dw * dw;
  }
#pragma unroll
  for (int off = 32; off; off >>= 1) vs += __shfl_xor(vs, off);
  float rs = rsqrtf(vs * (1.f / 768.f) + LN_EPS);
  ushort* orow = xn + (size_t)row * D_;
#pragma unroll
  for (int s = 0; s < 3; ++s) {
    int col = s * 256 + lane * 4;
    float4 g = *reinterpret_cast<const float4*>(gamma + col);
    float4 bb = *reinterpret_cast<const float4*>(beta + col);
    ushort4 o;
    o.x = f2bf((a[s].x - mu) * rs * g.x + bb.x);
    o.y = f2bf((a[s].y - mu) * rs * g.y + bb.y);
    o.z = f2bf((a[s].z - mu) * rs * g.z + bb.z);
    o.w = f2bf((a[s].w - mu) * rs * g.w + bb.w);
    *reinterpret_cast<ushort4*>(orow + col) = o;
  }
}

// ---------------- 256x256 superphase bf16 MFMA GEMM (r12 schedule) ----------------
// C[m,n] = sum_k A[m,k]*W[n,k].  K=768. 512 threads = 8 waves (2M x 4N).
// modes: 0 fp32 plain
//        5 cat -> sel0: d0 k bf16 row-major | sel1: d1 v FRAG tiles
//                 sel2: d2 r sigmoid, thread-ordered tiles | sel3: d3 z bf16 row-major
__global__ __launch_bounds__(512, 2) void gemm256(
    const ushort* __restrict__ A, const ushort* __restrict__ W,
    float* __restrict__ Cf,
    ushort* __restrict__ d0, ushort* __restrict__ d1,
    ushort* __restrict__ d2, ushort* __restrict__ d3, int mode) {
  __shared__ __align__(16) ushort lds[65536];  // 128 KiB
  const int tid = threadIdx.x;
  const int wid = tid >> 6;
  const int lane = tid & 63;
  const int wr = wid >> 2, wc = wid & 3;
  const int fr = lane & 15, fq = lane >> 4;
  const int m0 = blockIdx.x * 256, n0 = blockIdx.y * 256;
  const int strow = tid >> 3;
  const int stblk = tid & 7;

  const int RA0 = wr * 8192;
  const int RA1 = 32768 + wr * 8192;
  const int RB0 = 16384 + (wc >> 1) * 8192 + (wc & 1) * 4096;
  const int RB1 = 49152 + (wc >> 1) * 8192 + (wc & 1) * 4096;

  f32x4 acc[8][4];
#pragma unroll
  for (int m = 0; m < 8; ++m)
#pragma unroll
    for (int n = 0; n < 4; ++n) acc[m][n] = (f32x4){0.f, 0.f, 0.f, 0.f};

#define STAGE_HALF(gb, grow0, kk0, roff)                                          \
  {                                                                               \
    _Pragma("unroll") for (int j = 0; j < 2; ++j) {                               \
      const int lr_ = j * 64 + strow;                                             \
      const int bs_ = stblk ^ (lr_ & 7);                                          \
      const ushort* s_ = (gb) + (size_t)((grow0) + lr_) * 768 + (kk0) + bs_ * 8;  \
      __builtin_amdgcn_global_load_lds(                                           \
          (const __attribute__((address_space(1))) void*)s_,                      \
          (__attribute__((address_space(3))) void*)(lds + (roff) + j * 4096 + wid * 512), \
          16, 0, 0);                                                              \
    }                                                                             \
  }

#define LDF(dst, base, rf, kk)                                                    \
  dst = *reinterpret_cast<const bf16x8*>(                                         \
      lds + (base) + ((rf)*16 + fr) * 64 + ((((kk)*4 + fq) ^ (fr & 7)) * 8));

#define MFMA_Q(mb, nb, aa, bb)                                                    \
  _Pragma("unroll") for (int m_ = 0; m_ < 4; ++m_)                                \
  _Pragma("unroll") for (int n_ = 0; n_ < 2; ++n_)                                \
  _Pragma("unroll") for (int k_ = 0; k_ < 2; ++k_)                                \
    acc[(mb) + m_][(nb) + n_] = __builtin_amdgcn_mfma_f32_16x16x32_bf16(          \
        aa[m_][k_], bb[n_][k_], acc[(mb) + m_][(nb) + n_], 0, 0, 0);

#define LDF_AL(RA) \
  _Pragma("unroll") for (int m = 0; m < 4; ++m) { LDF(aL[m][0], RA, m, 0); LDF(aL[m][1], RA, m, 1); }
#define LDF_AH(RA) \
  _Pragma("unroll") for (int m = 0; m < 4; ++m) { LDF(aH[m][0], RA, m + 4, 0); LDF(aH[m][1], RA, m + 4, 1); }
#define LDF_BL(RB) \
  _Pragma("unroll") for (int n = 0; n < 2; ++n) { LDF(bL[n][0], RB, n, 0); LDF(bL[n][1], RB, n, 1); }
#define LDF_BH(RB) \
  _Pragma("unroll") for (int n = 0; n < 2; ++n) { LDF(bH[n][0], RB, n + 2, 0); LDF(bH[n][1], RB, n + 2, 1); }

  // ---- prologue: A0, B0 -> buf0; B1 -> buf1 ----
  STAGE_HALF(A, m0, 0, 0);
  STAGE_HALF(A, m0 + 128, 0, 8192);
  STAGE_HALF(W, n0, 0, 16384);
  STAGE_HALF(W, n0 + 128, 0, 24576);
  STAGE_HALF(W, n0, 64, 49152);
  STAGE_HALF(W, n0 + 128, 64, 57344);
  asm volatile("s_waitcnt vmcnt(4)" ::: "memory");
  __builtin_amdgcn_s_barrier();

  bf16x8 aL[4][2], aH[4][2], bL[2][2], bH[2][2];

  for (int i = 0; i < 6; ++i) {
    const int kQ = (2 * i + 1) * 64;
    const int kP2 = (2 * i + 2 <= 11 ? 2 * i + 2 : 11) * 64;
    const int kQ2 = (2 * i + 3 <= 11 ? 2 * i + 3 : 11) * 64;

    // ======== tile P = 2i (buf0) ========
    STAGE_HALF(A, m0, kQ, 32768);
    STAGE_HALF(A, m0 + 128, kQ, 40960);
    LDF_AL(RA0);
    LDF_BL(RB0);
    LDF_BH(RB0);
    __builtin_amdgcn_s_barrier();
    __builtin_amdgcn_s_setprio(1);
    MFMA_Q(0, 0, aL, bL);
    MFMA_Q(0, 2, aL, bH);
    __builtin_amdgcn_s_setprio(0);
    __builtin_amdgcn_s_barrier();
    STAGE_HALF(W, n0, kP2, 16384);
    STAGE_HALF(W, n0 + 128, kP2, 24576);
    LDF_AH(RA0);
    __builtin_amdgcn_s_barrier();
    __builtin_amdgcn_s_setprio(1);
    MFMA_Q(4, 0, aH, bL);
    MFMA_Q(4, 2, aH, bH);
    __builtin_amdgcn_s_setprio(0);
    asm volatile("s_waitcnt vmcnt(4)" ::: "memory");
    __builtin_amdgcn_s_barrier();

    // ======== tile Q = 2i+1 (buf1) ========
    STAGE_HALF(A, m0, kP2, 0);
    STAGE_HALF(A, m0 + 128, kP2, 8192);
    LDF_AL(RA1);
    LDF_BL(RB1);
    LDF_BH(RB1);
    __builtin_amdgcn_s_barrier();
    __builtin_amdgcn_s_setprio(1);
    MFMA_Q(0, 0, aL, bL);
    MFMA_Q(0, 2, aL, bH);
    __builtin_amdgcn_s_setprio(0);
    __builtin_amdgcn_s_barrier();
    STAGE_HALF(W, n0, kQ2, 49152);
    STAGE_HALF(W, n0 + 128, kQ2, 57344);
    LDF_AH(RA1);
    __builtin_amdgcn_s_barrier();
    __builtin_amdgcn_s_setprio(1);
    MFMA_Q(4, 0, aH, bL);
    MFMA_Q(4, 2, aH, bH);
    __builtin_amdgcn_s_setprio(0);
    asm volatile("s_waitcnt vmcnt(4)" ::: "memory");
    __builtin_amdgcn_s_barrier();
  }

  // ---- epilogue ----
  const int r0 = fq * 4;
  if (mode == 5) {
    const int sel = n0 >= 2304 ? 3 : n0 >= 1536 ? 2 : n0 >= 768 ? 1 : 0;
    const int nb = n0 - sel * 768;
    if (sel == 1) {
#pragma unroll
      for (int mf = 0; mf < 8; ++mf)
#pragma unroll
        for (int nf = 0; nf < 4; ++nf) {
          int gr = m0 + wr * 128 + mf * 16 + r0;
          int gc = nb + wc * 64 + nf * 16 + fr;
          int b = gr >> 11, t = gr & 2047;
          int c = t >> 6, s0 = t & 63;
          int h = gc >> 6, j = gc & 63;
          size_t addr = ((size_t)((b * 12 + h) * 32 + c)) * 4096 +
                        (size_t)(((j >> 4) * 2 + (s0 >> 5)) * 512 +
                                 (((s0 >> 3) & 3) * 16 + (j & 15)) * 8 + (s0 & 7));
          ushort4 o;
          o.x = f2bf(acc[mf][nf][0]); o.y = f2bf(acc[mf][nf][1]);
          o.z = f2bf(acc[mf][nf][2]); o.w = f2bf(acc[mf][nf][3]);
          *reinterpret_cast<ushort4*>(d1 + addr) = o;
        }
    } else if (sel == 2) {
      // r -> thread-ordered tiles: value(t,j) at chunkbase + ((t>>4)*64 +
      // ((t>>2)&3)*16 + (j&15))*16 + (j>>4)*4 + (t&3). rr=0..3 contiguous.
#pragma unroll
      for (int mf = 0; mf < 8; ++mf)
#pragma unroll
        for (int nf = 0; nf < 4; ++nf) {
          int gr = m0 + wr * 128 + mf * 16 + r0;
          int gc = nb + wc * 64 + nf * 16 + fr;
          int b = gr >> 11, t = gr & 2047;
          int c = t >> 6, tin = t & 63;
          int h = gc >> 6, j = gc & 63;
          size_t addr = ((size_t)((b * 12 + h) * 32 + c)) * 4096 +
                        (size_t)(((tin >> 4) * 64 + ((tin >> 2) & 3) * 16 + (j & 15)) * 16 +
                                 (j >> 4) * 4);
          ushort4 o;
          o.x = f2bf(1.f / (1.f + __expf(-acc[mf][nf][0])));
          o.y = f2bf(1.f / (1.f + __expf(-acc[mf][nf][1])));
          o.z = f2bf(1.f / (1.f + __expf(-acc[mf][nf][2])));
          o.w = f2bf(1.f / (1.f + __expf(-acc[mf][nf][3])));
          *reinterpret_cast<ushort4*>(d2 + addr) = o;
        }
    } else {
      ushort* dst = sel == 0 ? d0 : d3;
#pragma unroll
      for (int mf = 0; mf < 8; ++mf)
#pragma unroll
        for (int nf = 0; nf < 4; ++nf) {
          int gr = m0 + wr * 128 + mf * 16 + r0;
          int gc = nb + wc * 64 + nf * 16 + fr;
#pragma unroll
          for (int rr = 0; rr < 4; ++rr)
            dst[(size_t)(gr + rr) * 768 + gc] = f2bf(acc[mf][nf][rr]);
        }
    }
  } else {
#pragma unroll
    for (int mf = 0; mf < 8; ++mf)
#pragma unroll
      for (int nf = 0; nf < 4; ++nf) {
        int gr = m0 + wr * 128 + mf * 16 + r0;
        int gc = n0 + wc * 64 + nf * 16 + fr;
#pragma unroll
        for (int rr = 0; rr < 4; ++rr)
          Cf[(size_t)(gr + rr) * 768 + gc] = acc[mf][nf][rr];
      }
  }
#undef STAGE_HALF
#undef LDF
#undef MFMA_Q
#undef LDF_AL
#undef LDF_AH
#undef LDF_BL
#undef LDF_BH
}

// ---------------- scan P: per (bh,c): cumprod + Mc = kIA^T V (parallel) ------
__global__ __launch_bounds__(256) void scan_mc3(
    const ushort* __restrict__ kb, const ushort* __restrict__ zb,
    const ushort* __restrict__ vbF, const float* __restrict__ bwp,
    ushort* __restrict__ McT, float* __restrict__ aend) {
  __shared__ ushort kt[64 * 72];
  __shared__ ushort zt[64 * 72];
  __shared__ ushort kIAfA[4096];
  __shared__ float part[256];
  const int bh = blockIdx.x, c = blockIdx.y;
  const int b = bh / H_, h = bh % H_;
  const int tid = threadIdx.x;
  const int w = tid >> 6, lane = tid & 63;
  const int fr = lane & 15, fq = lane >> 4;
  const int row = tid >> 2, c16 = (tid & 3) * 16;
  const float bwh = bwp[h * 64];

  {
    const ushort* gk = kb + ((size_t)(b * T_ + c * TC + row)) * 768 + h * 64 + c16;
    const ushort* gz = zb + ((size_t)(b * T_ + c * TC + row)) * 768 + h * 64 + c16;
    uint4 k0 = *(const uint4*)gk, k1 = *(const uint4*)(gk + 8);
    uint4 z0 = *(const uint4*)gz, z1 = *(const uint4*)(gz + 8);
    *reinterpret_cast<uint4*>(&kt[row * 72 + c16]) = k0;
    *reinterpret_cast<uint4*>(&kt[row * 72 + c16 + 8]) = k1;
    *reinterpret_cast<uint4*>(&zt[row * 72 + c16]) = z0;
    *reinterpret_cast<uint4*>(&zt[row * 72 + c16 + 8]) = z1;
  }
  bf16x8 vfr[8];
  {
    const ushort* vch = vbF + ((size_t)bh * NC + c) * 4096;
#pragma unroll
    for (int f = 0; f < 8; ++f)
      vfr[f] = *reinterpret_cast<const bf16x8*>(vch + f * 512 + lane * 8);
  }
  __syncthreads();
  float dreg[16];
  float p = 1.f;
#pragma unroll
  for (int tt = 0; tt < 16; ++tt) {
    float z = bf2f(zt[(w * 16 + tt) * 72 + lane]);
    float d = 1.f / (1.f + __expf(z + bwh));
    dreg[tt] = d;
    p *= d;
  }
  part[w * 64 + lane] = p;
  __syncthreads();
  float a = 1.f;
  for (int w2 = 0; w2 < w; ++w2) a *= part[w2 * 64 + lane];
  if (w == 0)
    aend[((size_t)bh * NC + c) * 64 + lane] =
        part[lane] * part[64 + lane] * part[128 + lane] * part[192 + lane];
#pragma unroll
  for (int tt = 0; tt < 16; ++tt) {
    int t = w * 16 + tt;
    float k = bf2f(kt[t * 72 + lane]);
    a *= dreg[tt];
    kIAfA[fragaddr(lane, t)] = f2bf(k / a);  // A-frag (m=i, k=s)
  }
  __syncthreads();

  bf16x8 af2[2];
#pragma unroll
  for (int kk = 0; kk < 2; ++kk)
    af2[kk] = *reinterpret_cast<const bf16x8*>(&kIAfA[(w * 2 + kk) * 512 + lane * 8]);
  f32x4 accM[4];
#pragma unroll
  for (int nf = 0; nf < 4; ++nf) accM[nf] = (f32x4){0.f, 0.f, 0.f, 0.f};
#pragma unroll
  for (int kk = 0; kk < 2; ++kk)
#pragma unroll
    for (int nf = 0; nf < 4; ++nf)
      accM[nf] = __builtin_amdgcn_mfma_f32_16x16x32_bf16(af2[kk], vfr[nf * 2 + kk], accM[nf], 0, 0, 0);
  ushort* mch = McT + ((size_t)bh * NC + c) * 4096;
#pragma unroll
  for (int nf = 0; nf < 4; ++nf) {
    ushort4 o;
    o.x = f2bf(accM[nf][0]); o.y = f2bf(accM[nf][1]);
    o.z = f2bf(accM[nf][2]); o.w = f2bf(accM[nf][3]);
    *reinterpret_cast<ushort4*>(&mch[(nf * 16 + fr) * 64 + w * 16 + fq * 4]) = o;
  }
}

// ---------------- scan C: chain, widened (96x2 blocks, 8 elems/thread) -------
// S0_{c+1} = aend_c * (S0_c + Mc_c); S0F in B-frag layout (n=j, k=i).
__global__ __launch_bounds__(256) void scan_chain3(
    const ushort* __restrict__ McT, const float* __restrict__ aend,
    ushort* __restrict__ S0F) {
  const int bh = blockIdx.x;
  const int j = threadIdx.x >> 2;
  const int i0 = blockIdx.y * 32 + (threadIdx.x & 3) * 8;
  const int fbase = ((j >> 4) * 2 + (i0 >> 5)) * 512 + (((i0 >> 3) & 3) * 16 + (j & 15)) * 8;
  const ushort* mbase = McT + ((size_t)bh * NC) * 4096 + j * 64 + i0;
  const float* abase = aend + ((size_t)bh * NC) * 64 + i0;
  float S[8];
#pragma unroll
  for (int p = 0; p < 8; ++p) S[p] = 0.f;

  ushort4 m0 = *reinterpret_cast<const ushort4*>(mbase);
  ushort4 m1 = *reinterpret_cast<const ushort4*>(mbase + 4);
  float4 a0 = *(const float4*)(abase);
  float4 a1 = *(const float4*)(abase + 4);

  for (int c = 0; c < NC; ++c) {
    int cn = c + 1 < NC ? c + 1 : NC - 1;
    ushort4 n0 = *reinterpret_cast<const ushort4*>(mbase + (size_t)cn * 4096);
    ushort4 n1 = *reinterpret_cast<const ushort4*>(mbase + (size_t)cn * 4096 + 4);
    float4 b0 = *(const float4*)(abase + (size_t)cn * 64);
    float4 b1 = *(const float4*)(abase + (size_t)cn * 64 + 4);

    ushort* s0 = S0F + ((size_t)bh * NC + c) * 4096 + fbase;
    ushort4 o0, o1;
    o0.x = f2bf(S[0]); o0.y = f2bf(S[1]); o0.z = f2bf(S[2]); o0.w = f2bf(S[3]);
    o1.x = f2bf(S[4]); o1.y = f2bf(S[5]); o1.z = f2bf(S[6]); o1.w = f2bf(S[7]);
    *reinterpret_cast<ushort4*>(s0) = o0;
    *reinterpret_cast<ushort4*>(s0 + 4) = o1;

    S[0] = a0.x * (S[0] + bf2f(m0.x));
    S[1] = a0.y * (S[1] + bf2f(m0.y));
    S[2] = a0.z * (S[2] + bf2f(m0.z));
    S[3] = a0.w * (S[3] + bf2f(m0.w));
    S[4] = a1.x * (S[4] + bf2f(m1.x));
    S[5] = a1.y * (S[5] + bf2f(m1.y));
    S[6] = a1.z * (S[6] + bf2f(m1.z));
    S[7] = a1.w * (S[7] + bf2f(m1.w));

    m0 = n0; m1 = n1; a0 = b0; a1 = b1;
  }
}

// ---------------- scan Y: per (bh,c): A = causal(kA.kIA^T); y = kA.S0F + A.V --
__global__ __launch_bounds__(256, 2) void scan_y3(
    const ushort* __restrict__ kb, const ushort* __restrict__ zb,
    const ushort* __restrict__ vbF, const ushort* __restrict__ rbF,
    const ushort* __restrict__ S0F, const float* __restrict__ bwp,
    ushort* __restrict__ yrow) {
  __shared__ ushort kt[64 * 72];
  __shared__ ushort zt[64 * 72];
  __shared__ ushort kAf[4096];
  __shared__ ushort kIAfB[4096];
  __shared__ ushort Am[64 * 72];
  __shared__ float part[256];
  const int bh = blockIdx.x, c = blockIdx.y;
  const int b = bh / H_, h = bh % H_;
  const int tid = threadIdx.x;
  const int w = tid >> 6, lane = tid & 63;
  const int fr = lane & 15, fq = lane >> 4;
  const int row = tid >> 2, c16 = (tid & 3) * 16;
  const float bwh = bwp[h * 64];
  const int swz = fragswz(lane);

  // early-issue all independent global loads (hide under cumprod)
  {
    const ushort* gk = kb + ((size_t)(b * T_ + c * TC + row)) * 768 + h * 64 + c16;
    const ushort* gz = zb + ((size_t)(b * T_ + c * TC + row)) * 768 + h * 64 + c16;
    uint4 k0 = *(const uint4*)gk, k1 = *(const uint4*)(gk + 8);
    uint4 z0 = *(const uint4*)gz, z1 = *(const uint4*)(gz + 8);
    *reinterpret_cast<uint4*>(&kt[row * 72 + c16]) = k0;
    *reinterpret_cast<uint4*>(&kt[row * 72 + c16 + 8]) = k1;
    *reinterpret_cast<uint4*>(&zt[row * 72 + c16]) = z0;
    *reinterpret_cast<uint4*>(&zt[row * 72 + c16 + 8]) = z1;
  }
  bf16x8 vfr[8], s0fr[8];
  {
    const ushort* vch = vbF + ((size_t)bh * NC + c) * 4096;
    const ushort* s0ch = S0F + ((size_t)bh * NC + c) * 4096;
#pragma unroll
    for (int f = 0; f < 8; ++f) {
      vfr[f] = *reinterpret_cast<const bf16x8*>(vch + f * 512 + lane * 8);
      s0fr[f] = *reinterpret_cast<const bf16x8*>(s0ch + f * 512 + lane * 8);
    }
  }
  ushort4 rp0, rp1, rp2, rp3;
  {
    const ushort* rch = rbF + ((size_t)bh * NC + c) * 4096 + tid * 16;
    rp0 = *reinterpret_cast<const ushort4*>(rch);
    rp1 = *reinterpret_cast<const ushort4*>(rch + 4);
    rp2 = *reinterpret_cast<const ushort4*>(rch + 8);
    rp3 = *reinterpret_cast<const ushort4*>(rch + 12);
  }
  const ushort rl[16] = {rp0.x, rp0.y, rp0.z, rp0.w, rp1.x, rp1.y, rp1.z, rp1.w,
                         rp2.x, rp2.y, rp2.z, rp2.w, rp3.x, rp3.y, rp3.z, rp3.w};
  __syncthreads();
  float dreg[16];
  float p = 1.f;
#pragma unroll
  for (int tt = 0; tt < 16; ++tt) {
    float z = bf2f(zt[(w * 16 + tt) * 72 + lane]);
    float d = 1.f / (1.f + __expf(z + bwh));
    dreg[tt] = d;
    p *= d;
  }
  part[w * 64 + lane] = p;
  __syncthreads();
  float a = 1.f;
  for (int w2 = 0; w2 < w; ++w2) a *= part[w2 * 64 + lane];
#pragma unroll
  for (int tt = 0; tt < 16; ++tt) {
    int t = w * 16 + tt;
    float k = bf2f(kt[t * 72 + lane]);
    a *= dreg[tt];
    int ad = fragaddr(t, lane) ^ swz;
    kAf[ad] = f2bf(k * a);
    kIAfB[ad] = f2bf(k / a);
  }
  __syncthreads();

  bf16x8 af[2];
#pragma unroll
  for (int kk = 0; kk < 2; ++kk) {
    int ra = ((w * 2 + kk) * 512 + lane * 8) ^ (((lane >> 4) << 3) ^ (kk << 5));
    af[kk] = *reinterpret_cast<const bf16x8*>(&kAf[ra]);
  }
  {
    f32x4 accA[4];
#pragma unroll
    for (int nf = 0; nf < 4; ++nf) accA[nf] = (f32x4){0.f, 0.f, 0.f, 0.f};
#pragma unroll
    for (int kk = 0; kk < 2; ++kk)
#pragma unroll
      for (int nf = 0; nf < 4; ++nf) {
        int rb8 = ((nf * 2 + kk) * 512 + lane * 8) ^ (((lane >> 4) << 3) ^ (kk << 5));
        bf16x8 b8 = *reinterpret_cast<const bf16x8*>(&kIAfB[rb8]);
        accA[nf] = __builtin_amdgcn_mfma_f32_16x16x32_bf16(af[kk], b8, accA[nf], 0, 0, 0);
      }
#pragma unroll
    for (int nf = 0; nf < 4; ++nf)
#pragma unroll
      for (int q = 0; q < 4; ++q) {
        int t = w * 16 + fq * 4 + q;
        int s = nf * 16 + fr;
        Am[t * 72 + s] = f2bf((s <= t) ? accA[nf][q] : 0.f);
      }
  }
  __syncthreads();

  f32x4 accY[4];
#pragma unroll
  for (int nf = 0; nf < 4; ++nf) accY[nf] = (f32x4){0.f, 0.f, 0.f, 0.f};
#pragma unroll
  for (int kk = 0; kk < 2; ++kk)
#pragma unroll
    for (int nf = 0; nf < 4; ++nf)
      accY[nf] = __builtin_amdgcn_mfma_f32_16x16x32_bf16(af[kk], s0fr[nf * 2 + kk], accY[nf], 0, 0, 0);
#pragma unroll
  for (int kk = 0; kk < 2; ++kk) {
    bf16x8 am8 = *reinterpret_cast<const bf16x8*>(&Am[(w * 16 + fr) * 72 + kk * 32 + fq * 8]);
#pragma unroll
    for (int nf = 0; nf < 4; ++nf)
      accY[nf] = __builtin_amdgcn_mfma_f32_16x16x32_bf16(am8, vfr[nf * 2 + kk], accY[nf], 0, 0, 0);
  }
#pragma unroll
  for (int nf = 0; nf < 4; ++nf)
#pragma unroll
    for (int q = 0; q < 4; ++q) {
      int t = w * 16 + fq * 4 + q;
      int j = nf * 16 + fr;
      size_t go = ((size_t)(b * T_ + c * TC + t)) * 768 + h * 64 + j;
      yrow[go] = f2bf(accY[nf][q] * bf2f(rl[nf * 4 + q]));
    }
}

// ---------------- launch ----------------
extern "C" void kernel_launch(void* const* d_in, const int* in_sizes, int n_in,
                              void* d_out, int out_size, void* d_ws, size_t ws_size,
                              hipStream_t stream) {
  const float* x     = (const float*)d_in[0];
  const float* Wx    = (const float*)d_in[1];
  const float* Ww    = (const float*)d_in[2];
  const float* bw    = (const float*)d_in[3];
  const float* Wk    = (const float*)d_in[4];
  const float* Wv    = (const float*)d_in[5];
  const float* Wr    = (const float*)d_in[6];
  const float* Wo    = (const float*)d_in[7];
  const float* gamma = (const float*)d_in[8];
  const float* beta  = (const float*)d_in[9];
  float* out = (float*)d_out;

  // workspace (bytes), NEED proven rounds 3-12:
  //   xn   [0,          25165824)  bf16 xn -> McT (after cat)
  //   wb   [25165824,   32243712)  6 slots: Wk,Wv,Wr,M,Wo,Ww
  //   WxT  [32243712,   57409536)  WxT (dead after M-gemm) -> S0F
  //   kb   [57409536,   82575360)
  //   vbF  [82575360,  107741184)  v fragment tiles per (bh,c)
  //   rbF  [107741184, 132907008)  r thread-ordered tiles per (bh,c)
  //   yr   [132907008, 158072832)  head = aend fp32 (dead before scan_y3 writes)
  //   zb   [158072832, 183238656)  bf16 z
  const size_t NEED = 208404480ull;
  if (ws_size < NEED) {
    zero_out_kernel<<<2048, 256, 0, stream>>>(out, out_size);
    return;
  }

  char* ws = (char*)d_ws;
  ushort* xn  = (ushort*)ws;
  ushort* wb  = (ushort*)(ws + 25165824);
  ushort* WxT = (ushort*)(ws + 32243712);
  ushort* kb  = (ushort*)(ws + 57409536);
  ushort* vbF = (ushort*)(ws + 82575360);
  ushort* rbF = (ushort*)(ws + 107741184);
  ushort* yr  = (ushort*)(ws + 132907008);
  ushort* zb  = (ushort*)(ws + 158072832);
  ushort* McT = (ushort*)ws;                 // aliases xn (dead after cat)
  ushort* S0F = (ushort*)(ws + 32243712);    // aliases WxT (dead after M-gemm)
  float*  aendb = (float*)(ws + 132907008);  // yr head (dead before scan_y3)

  ushort* WcatB = wb;                 // slots 0..3: Wk, Wv, Wr, M
  ushort* Mb  = wb + 3 * 589824;
  ushort* WoB = wb + 4 * 589824;
  ushort* WwB = wb + 5 * 589824;

  prep_kernel<<<dim3(576, 6), 256, 0, stream>>>(Wk, Wv, Wr, Wo, Ww, Wx, wb, WxT);
  // composite M = Ww @ Wx
  gemm256<<<dim3(3, 3), 512, 0, stream>>>(WwB, WxT, nullptr, Mb, nullptr, nullptr,
                                          nullptr, 5);
  ln_kernel<<<4096, 256, 0, stream>>>(x, gamma, beta, xn);

  // fused k/v/r/z GEMM (N=3072): k bf16, v frag, r thread-tiles sigmoid, z bf16
  gemm256<<<dim3(64, 12), 512, 0, stream>>>(xn, WcatB, nullptr, kb, vbF, rbF, zb, 5);

  scan_mc3<<<dim3(96, NC), 256, 0, stream>>>(kb, zb, vbF, bw, McT, aendb);
  scan_chain3<<<dim3(96, 2), 256, 0, stream>>>(McT, aendb, S0F);
  scan_y3<<<dim3(96, NC), 256, 0, stream>>>(kb, zb, vbF, rbF, S0F, bw, yr);

  // final GEMM (N=768): fp32 out
  gemm256<<<dim3(64, 3), 512, 0, stream>>>(yr, WoB, out, nullptr, nullptr, nullptr,
                                           nullptr, 0);
}